// Round 8
// baseline (313.625 us; speedup 1.0000x reference)
//
#include <hip/hip_runtime.h>
#include <hip/hip_fp16.h>

// GCN: 2x (linear -> deg-normalized scatter-add -> bias -> tanh) -> linear(1) -> softmax(N)
// R7: column-split aggregation — features stored as two half-matrices (dims 0-63,
// 64-127; 12.8 MB each). Each aggregate runs as 2 passes with halved working set
// -> better per-XCD L2 hit on the random gather. 8 lanes/edge, 8 edges/wave-iter
// (same VALU/byte as before). MFMA GEMM + bucket-sort CSR unchanged.

#define BSHIFT 9
#define BSPAN  512
#define PCHUNK 4096
#define LCAP   12288

typedef _Float16 half8 __attribute__((ext_vector_type(8)));
typedef float floatx4 __attribute__((ext_vector_type(4)));

__device__ inline void fmix2(float& a0, float& a1, unsigned int h2) {
    asm("v_fma_mix_f32 %0, %1, 1.0, %0 op_sel:[0,0,0] op_sel_hi:[1,0,0]" : "+v"(a0) : "v"(h2));
    asm("v_fma_mix_f32 %0, %1, 1.0, %0 op_sel:[1,0,0] op_sel_hi:[1,0,0]" : "+v"(a1) : "v"(h2));
}
__device__ inline void fmix_acc8(float* acc, uint4 v) {
    fmix2(acc[0], acc[1], v.x);
    fmix2(acc[2], acc[3], v.y);
    fmix2(acc[4], acc[5], v.z);
    fmix2(acc[6], acc[7], v.w);
}

// exact-saturating fast tanh: 1 - 2/(e^2x + 1)
__device__ inline float tanh_fast(float x) {
    float e = __expf(2.0f * x);
    return 1.0f - 2.0f * __builtin_amdgcn_rcpf(e + 1.0f);
}

__device__ inline uint4 f_to_h8(const float* f) {
    uint4 v;
    v.x = __builtin_bit_cast(unsigned int, __floats2half2_rn(f[0], f[1]));
    v.y = __builtin_bit_cast(unsigned int, __floats2half2_rn(f[2], f[3]));
    v.z = __builtin_bit_cast(unsigned int, __floats2half2_rn(f[4], f[5]));
    v.w = __builtin_bit_cast(unsigned int, __floats2half2_rn(f[6], f[7]));
    return v;
}

// ---------------- CSR build (2-level bucket counting sort) ----------------
__global__ __launch_bounds__(256) void hist_buckets(const int* __restrict__ col, int E,
                                                    int* __restrict__ bucketCnt) {
    __shared__ int h[256];
    h[threadIdx.x] = 0;
    __syncthreads();
    for (int e = blockIdx.x * 256 + threadIdx.x; e < E; e += gridDim.x * 256)
        atomicAdd(&h[col[e] >> BSHIFT], 1);
    __syncthreads();
    int v = h[threadIdx.x];
    if (v) atomicAdd(&bucketCnt[threadIdx.x], v);
}

__global__ void scan_buckets(const int* __restrict__ cnt, int* __restrict__ bucketPtr,
                             int* __restrict__ cursor, int NB, int E) {
    __shared__ int s[256];
    int t = threadIdx.x;
    int v = (t < NB) ? cnt[t] : 0;
    s[t] = v;
    __syncthreads();
    for (int d = 1; d < 256; d <<= 1) {
        int x = (t >= d) ? s[t - d] : 0;
        __syncthreads();
        s[t] += x;
        __syncthreads();
    }
    if (t < NB) {
        int p = s[t] - v;
        bucketPtr[t] = p;
        cursor[t] = p;
    }
    if (t == 0) bucketPtr[NB] = E;
}

// pairs packed: (src << BSHIFT) | (dst & (BSPAN-1))   [src < 2^23]
__global__ __launch_bounds__(256) void partition_edges(const int* __restrict__ row,
                                                       const int* __restrict__ col, int E,
                                                       int* __restrict__ cursor,
                                                       unsigned int* __restrict__ pairs) {
    __shared__ int hist[256], sscan[256], gdelta[256], hcur[256];
    __shared__ uint2 stage[PCHUNK];
    int t = threadIdx.x;
    int base = blockIdx.x * PCHUNK;
    int cnt = min(PCHUNK, E - base);
    hist[t] = 0;
    __syncthreads();
    uint2 v[16];
    int b_[16];
#pragma unroll
    for (int k = 0; k < 16; k++) {
        int idx = t + k * 256;
        if (idx < cnt) {
            int c = col[base + idx], r = row[base + idx];
            v[k] = make_uint2((unsigned)c, (unsigned)r);
            b_[k] = c >> BSHIFT;
            atomicAdd(&hist[b_[k]], 1);
        } else b_[k] = -1;
    }
    __syncthreads();
    int hv = hist[t];
    sscan[t] = hv;
    __syncthreads();
    for (int d = 1; d < 256; d <<= 1) {
        int x = (t >= d) ? sscan[t - d] : 0;
        __syncthreads();
        sscan[t] += x;
        __syncthreads();
    }
    int excl = sscan[t] - hv;
    if (hv > 0) {
        int g = atomicAdd(&cursor[t], hv);
        gdelta[t] = g - excl;
    }
    hcur[t] = excl;
    __syncthreads();
#pragma unroll
    for (int k = 0; k < 16; k++) {
        if (b_[k] >= 0) {
            int slot = atomicAdd(&hcur[b_[k]], 1);
            stage[slot] = v[k];
        }
    }
    __syncthreads();
    for (int i = t; i < cnt; i += 256) {
        uint2 p = stage[i];
        pairs[gdelta[p.x >> BSHIFT] + i] = (p.y << BSHIFT) | (p.x & (BSPAN - 1));
    }
}

__global__ __launch_bounds__(256) void build_bucket_csr(const unsigned int* __restrict__ pairs,
                                                        const int* __restrict__ bucketPtr,
                                                        int* __restrict__ rowptr,
                                                        float* __restrict__ dinv,
                                                        int* __restrict__ csr,
                                                        int n, int NB, int E) {
    __shared__ int hist[BSPAN];
    __shared__ int lptr[BSPAN];
    __shared__ int s[256];
    __shared__ int srcStage[LCAP];
    int b = blockIdx.x, t = threadIdx.x;
    int base = bucketPtr[b], cnt = bucketPtr[b + 1] - base;
    int node0 = b << BSHIFT;
    int nn = min(BSPAN, n - node0);
    hist[t] = 0; hist[t + 256] = 0;
    __syncthreads();
    for (int i = t; i < cnt; i += 256)
        atomicAdd(&hist[pairs[base + i] & (BSPAN - 1)], 1);
    __syncthreads();
    int a0 = hist[2 * t], a1 = hist[2 * t + 1];
    int sum = a0 + a1;
    s[t] = sum;
    __syncthreads();
    for (int d = 1; d < 256; d <<= 1) {
        int x = (t >= d) ? s[t - d] : 0;
        __syncthreads();
        s[t] += x;
        __syncthreads();
    }
    int excl = s[t] - sum;
    lptr[2 * t] = excl;
    lptr[2 * t + 1] = excl + a0;
    __syncthreads();
    for (int lc = t; lc < nn; lc += 256) {
        rowptr[node0 + lc] = base + lptr[lc];
        dinv[node0 + lc] = rsqrtf((float)(hist[lc] + 1));
    }
    if (b == NB - 1 && t == 0) rowptr[n] = E;
    __syncthreads();
    hist[t] = 0; hist[t + 256] = 0;
    __syncthreads();
    bool inLds = (cnt <= LCAP);
    for (int i = t; i < cnt; i += 256) {
        unsigned int p = pairs[base + i];
        int lc = p & (BSPAN - 1);
        int rank = atomicAdd(&hist[lc], 1);
        int slot = lptr[lc] + rank;
        if (inLds) srcStage[slot] = (int)(p >> BSHIFT);
        else csr[base + slot] = (int)(p >> BSHIFT);
    }
    __syncthreads();
    if (inLds)
        for (int i = t; i < cnt; i += 256) csr[base + i] = srcStage[i];
}

// ---------------- W1,W2 -> B-fragment layout (fp16), one launch ----------------
__global__ __launch_bounds__(256) void prep_wfrags(const float* __restrict__ W1,
                                                   const float* __restrict__ W2,
                                                   uint4* __restrict__ F1,
                                                   uint4* __restrict__ F2) {
    int g = blockIdx.x * 256 + threadIdx.x;   // 0..4095
    const float* W = (g < 2048) ? W1 : W2;
    uint4* F = (g < 2048) ? F1 : F2;
    int t = g & 2047;
    int lane = t & 63, ct = (t >> 6) & 7, ks = t >> 9;
    int col = ct * 16 + (lane & 15);
    int kb = ks * 32 + (lane >> 4) * 8;
    half8 v;
#pragma unroll
    for (int j = 0; j < 8; j++) v[j] = (_Float16)W[(kb + j) * 128 + col];
    F[t] = __builtin_bit_cast(uint4, v);
}

// ---------------- MFMA GEMM: [C0|C1](r,:) = fp16( dinv[r] * (A[r,:] @ W) ) --------
// A: fp32 (layer 1) or split fp16 halves (layer 2). Output split into 64-dim halves.
template <bool HALF_IN>
__global__ __launch_bounds__(256) void gemm_mfma(const float* __restrict__ Af,
                                                 const uint4* __restrict__ Ah0,
                                                 const uint4* __restrict__ Ah1,
                                                 const uint4* __restrict__ F,
                                                 const float* __restrict__ dinv,
                                                 unsigned short* __restrict__ C0,
                                                 unsigned short* __restrict__ C1,
                                                 int n) {
    int w = threadIdx.x >> 6, lane = threadIdx.x & 63;
    int r0 = blockIdx.x * 128 + w * 32;
    int rA0 = r0 + (lane & 15);
    int rA1 = rA0 + 16;
    int kc = lane >> 4;
    floatx4 acc[2][8] = {};

#pragma unroll
    for (int ks = 0; ks < 4; ks++) {
        int c16 = ks * 4 + kc;               // 16B-chunk index within the 256B row
        half8 a0 = {}, a1 = {};
        if constexpr (HALF_IN) {
            const uint4* src = (c16 < 8) ? Ah0 : Ah1;
            int ci = (c16 < 8) ? c16 : c16 - 8;
            if (rA0 < n) a0 = __builtin_bit_cast(half8, src[(size_t)rA0 * 8 + ci]);
            if (rA1 < n) a1 = __builtin_bit_cast(half8, src[(size_t)rA1 * 8 + ci]);
        } else {
            if (rA0 < n) {
                const float4* p = (const float4*)&Af[(size_t)rA0 * 128 + c16 * 8];
                float4 u = p[0], v = p[1];
                a0[0] = (_Float16)u.x; a0[1] = (_Float16)u.y; a0[2] = (_Float16)u.z; a0[3] = (_Float16)u.w;
                a0[4] = (_Float16)v.x; a0[5] = (_Float16)v.y; a0[6] = (_Float16)v.z; a0[7] = (_Float16)v.w;
            }
            if (rA1 < n) {
                const float4* p = (const float4*)&Af[(size_t)rA1 * 128 + c16 * 8];
                float4 u = p[0], v = p[1];
                a1[0] = (_Float16)u.x; a1[1] = (_Float16)u.y; a1[2] = (_Float16)u.z; a1[3] = (_Float16)u.w;
                a1[4] = (_Float16)v.x; a1[5] = (_Float16)v.y; a1[6] = (_Float16)v.z; a1[7] = (_Float16)v.w;
            }
        }
        half8 b[8];
#pragma unroll
        for (int ct = 0; ct < 8; ct++)
            b[ct] = __builtin_bit_cast(half8, F[ks * 512 + ct * 64 + lane]);
#pragma unroll
        for (int ct = 0; ct < 8; ct++) {
            acc[0][ct] = __builtin_amdgcn_mfma_f32_16x16x32_f16(a0, b[ct], acc[0][ct], 0, 0, 0);
            acc[1][ct] = __builtin_amdgcn_mfma_f32_16x16x32_f16(a1, b[ct], acc[1][ct], 0, 0, 0);
        }
    }

#pragma unroll
    for (int rt = 0; rt < 2; rt++) {
        int rbase = r0 + rt * 16 + (lane >> 4) * 4;
#pragma unroll
        for (int reg = 0; reg < 4; reg++) {
            int r = rbase + reg;
            if (r < n) {
                float di = dinv[r];
#pragma unroll
                for (int ct = 0; ct < 8; ct++) {
                    _Float16 h = (_Float16)(acc[rt][ct][reg] * di);
                    unsigned short* C = (ct < 4) ? C0 : C1;
                    C[(size_t)r * 64 + (ct & 3) * 16 + (lane & 15)] =
                        __builtin_bit_cast(unsigned short, h);
                }
            }
        }
    }
}

// ---------------- aggregation over one 64-dim half ----------------
// wave/node; 8 lanes/edge (uint4 = 8 fp16/lane), 8 edges/iter; T pre-scaled by dinv.
__global__ __launch_bounds__(256) void aggregate_h(const uint4* __restrict__ T,
                                                   const int* __restrict__ csr,
                                                   const int* __restrict__ rowptr,
                                                   const float* __restrict__ dinv,
                                                   const float* __restrict__ biasHalf,
                                                   uint4* __restrict__ Out, int n) {
    int node = (int)((blockIdx.x * 256 + threadIdx.x) >> 6);
    int lane = threadIdx.x & 63;
    if (node >= n) return;
    int grp = lane >> 3, m = lane & 7;

    float acc[8] = {};
    int beg = rowptr[node], end = rowptr[node + 1];
    int e = beg;
    while (e < end) {
        int take = min(end - e, 64);
        int myidx = (lane < take) ? csr[e + lane] : 0;
#pragma unroll 2
        for (int j = 0; j < take; j += 8) {
            int src = __shfl(myidx, j + grp);
            if (j + grp < take) {
                uint4 v = T[(size_t)src * 8 + m];
                fmix_acc8(acc, v);
            }
        }
        e += take;
    }
#pragma unroll
    for (int q = 0; q < 8; q++) {
        acc[q] += __shfl_xor(acc[q], 8);
        acc[q] += __shfl_xor(acc[q], 16);
        acc[q] += __shfl_xor(acc[q], 32);
    }

    fmix_acc8(acc, T[(size_t)node * 8 + m]);   // self loop
    float di = dinv[node];
    const float4* bp = (const float4*)&biasHalf[m * 8];
    float4 b0 = bp[0], b1 = bp[1];
    float bb[8] = {b0.x, b0.y, b0.z, b0.w, b1.x, b1.y, b1.z, b1.w};
    float o[8];
#pragma unroll
    for (int q = 0; q < 8; q++) o[q] = tanh_fast(acc[q] * di + bb[q]);
    if (grp == 0) Out[(size_t)node * 8 + m] = f_to_h8(o);
}

// same over one half, fused with half of the classifier dot; ADD accumulates pass 2
template <bool ADD>
__global__ __launch_bounds__(256) void aggregate_logits_h(const uint4* __restrict__ T,
                                                          const int* __restrict__ csr,
                                                          const int* __restrict__ rowptr,
                                                          const float* __restrict__ dinv,
                                                          const float* __restrict__ biasHalf,
                                                          const float* __restrict__ WcHalf,
                                                          const float* __restrict__ bc,
                                                          float* __restrict__ logits, int n) {
    int node = (int)((blockIdx.x * 256 + threadIdx.x) >> 6);
    int lane = threadIdx.x & 63;
    if (node >= n) return;
    int grp = lane >> 3, m = lane & 7;

    float acc[8] = {};
    int beg = rowptr[node], end = rowptr[node + 1];
    int e = beg;
    while (e < end) {
        int take = min(end - e, 64);
        int myidx = (lane < take) ? csr[e + lane] : 0;
#pragma unroll 2
        for (int j = 0; j < take; j += 8) {
            int src = __shfl(myidx, j + grp);
            if (j + grp < take) {
                uint4 v = T[(size_t)src * 8 + m];
                fmix_acc8(acc, v);
            }
        }
        e += take;
    }
#pragma unroll
    for (int q = 0; q < 8; q++) {
        acc[q] += __shfl_xor(acc[q], 8);
        acc[q] += __shfl_xor(acc[q], 16);
        acc[q] += __shfl_xor(acc[q], 32);
    }

    fmix_acc8(acc, T[(size_t)node * 8 + m]);   // self loop
    float di = dinv[node];
    const float4* bp = (const float4*)&biasHalf[m * 8];
    float4 b0 = bp[0], b1 = bp[1];
    float bb[8] = {b0.x, b0.y, b0.z, b0.w, b1.x, b1.y, b1.z, b1.w};
    const float4* wp = (const float4*)&WcHalf[m * 8];
    float4 w0 = wp[0], w1 = wp[1];
    float ww[8] = {w0.x, w0.y, w0.z, w0.w, w1.x, w1.y, w1.z, w1.w};
    float d = 0.0f;
#pragma unroll
    for (int q = 0; q < 8; q++) d += tanh_fast(acc[q] * di + bb[q]) * ww[q];
    // reduce across the 8 dim-chunks (groups already merged)
    d += __shfl_xor(d, 1);
    d += __shfl_xor(d, 2);
    d += __shfl_xor(d, 4);
    if (lane == 0) {
        if constexpr (ADD) logits[node] += d;
        else logits[node] = d + bc[0];
    }
}

// ---------------- softmax over N ----------------
__global__ __launch_bounds__(256) void maxpart(const float* __restrict__ logits, int n,
                                               float* __restrict__ partialMax,
                                               float* __restrict__ denom) {
    if (blockIdx.x == 0 && threadIdx.x == 0) *denom = 0.0f;
    __shared__ float s[256];
    float m = -3.4e38f;
    for (int i = blockIdx.x * 256 + threadIdx.x; i < n; i += 256 * 256)
        m = fmaxf(m, logits[i]);
    s[threadIdx.x] = m;
    __syncthreads();
    for (int d = 128; d; d >>= 1) {
        if (threadIdx.x < d) s[threadIdx.x] = fmaxf(s[threadIdx.x], s[threadIdx.x + d]);
        __syncthreads();
    }
    if (threadIdx.x == 0) partialMax[blockIdx.x] = s[0];
}

__global__ __launch_bounds__(256) void exp_kernel(const float* __restrict__ logits,
                                                  const float* __restrict__ partialMax,
                                                  float* __restrict__ outv,
                                                  float* __restrict__ denom, int n) {
    __shared__ float s[256];
    s[threadIdx.x] = partialMax[threadIdx.x];
    __syncthreads();
    for (int d = 128; d; d >>= 1) {
        if (threadIdx.x < d) s[threadIdx.x] = fmaxf(s[threadIdx.x], s[threadIdx.x + d]);
        __syncthreads();
    }
    float maxv = s[0];
    __syncthreads();
    int i = blockIdx.x * 256 + threadIdx.x;
    float e = 0.0f;
    if (i < n) {
        e = expf(logits[i] - maxv);
        outv[i] = e;
    }
    s[threadIdx.x] = e;
    __syncthreads();
    for (int d = 128; d; d >>= 1) {
        if (threadIdx.x < d) s[threadIdx.x] += s[threadIdx.x + d];
        __syncthreads();
    }
    if (threadIdx.x == 0) atomicAdd(denom, s[0]);
}

__global__ __launch_bounds__(256) void norm_kernel(float* __restrict__ out,
                                                   const float* __restrict__ denom, int n) {
    int i = blockIdx.x * 256 + threadIdx.x;
    if (i < n) out[i] = out[i] / (*denom);
}

extern "C" void kernel_launch(void* const* d_in, const int* in_sizes, int n_in,
                              void* d_out, int out_size, void* d_ws, size_t ws_size,
                              hipStream_t stream) {
    const float* x  = (const float*)d_in[0];
    const int*   ei = (const int*)d_in[1];   // [2,E] int32 (JAX x64 disabled)
    const float* W1 = (const float*)d_in[2];
    const float* b1 = (const float*)d_in[3];
    const float* W2 = (const float*)d_in[4];
    const float* b2 = (const float*)d_in[5];
    const float* Wc = (const float*)d_in[6];
    const float* bc = (const float*)d_in[7];

    int n = in_sizes[0] / 128;
    int E = in_sizes[1] / 2;
    const int* row = ei;
    const int* col = ei + E;
    int NB = (n + BSPAN - 1) >> BSHIFT;

    char* ws = (char*)d_ws;
    size_t off = 0;
    auto alloc = [&](size_t bytes) -> void* {
        void* p = ws + off;
        off += (bytes + 255) & ~(size_t)255;
        return p;
    };
    uint4*  A0       = (uint4*)alloc((size_t)n * 64 * 2);   // fp16 half features
    uint4*  A1       = (uint4*)alloc((size_t)n * 64 * 2);
    uint4*  B0       = (uint4*)alloc((size_t)n * 64 * 2);
    uint4*  B1       = (uint4*)alloc((size_t)n * 64 * 2);
    unsigned int* pairs = (unsigned int*)alloc((size_t)E * 4);
    int*    csr      = (int*)alloc((size_t)E * 4);
    float*  dinv     = (float*)alloc((size_t)n * 4);
    int*    rowptr   = (int*)alloc((size_t)(n + 1) * 4);
    int*    bucketCnt= (int*)alloc(256 * 4);
    int*    bucketPtr= (int*)alloc(257 * 4);
    int*    cursor   = (int*)alloc(256 * 4);
    uint4*  F1       = (uint4*)alloc(2048 * 16);
    uint4*  F2       = (uint4*)alloc(2048 * 16);
    float*  logits   = (float*)alloc((size_t)n * 4);
    float*  pmax     = (float*)alloc(256 * 4);
    float*  denom    = (float*)alloc(4);

    int nbN = (n + 255) / 256;
    int nbW = (n + 3) / 4;
    int nbG = (n + 127) / 128;

    hipMemsetAsync(bucketCnt, 0, 256 * 4, stream);

    hist_buckets<<<512, 256, 0, stream>>>(col, E, bucketCnt);
    scan_buckets<<<1, 256, 0, stream>>>(bucketCnt, bucketPtr, cursor, NB, E);
    partition_edges<<<(E + PCHUNK - 1) / PCHUNK, 256, 0, stream>>>(row, col, E, cursor, pairs);
    prep_wfrags<<<16, 256, 0, stream>>>(W1, W2, F1, F2);
    build_bucket_csr<<<NB, 256, 0, stream>>>(pairs, bucketPtr, rowptr, dinv, csr, n, NB, E);

    gemm_mfma<false><<<nbG, 256, 0, stream>>>(x, nullptr, nullptr, F1, dinv,
                                              (unsigned short*)A0, (unsigned short*)A1, n);
    aggregate_h<<<nbW, 256, 0, stream>>>(A0, csr, rowptr, dinv, b1, B0, n);
    aggregate_h<<<nbW, 256, 0, stream>>>(A1, csr, rowptr, dinv, b1 + 64, B1, n);
    gemm_mfma<true><<<nbG, 256, 0, stream>>>(nullptr, B0, B1, F2, dinv,
                                             (unsigned short*)A0, (unsigned short*)A1, n);
    aggregate_logits_h<false><<<nbW, 256, 0, stream>>>(A0, csr, rowptr, dinv, b2, Wc, bc,
                                                       logits, n);
    aggregate_logits_h<true><<<nbW, 256, 0, stream>>>(A1, csr, rowptr, dinv, b2 + 64, Wc + 64,
                                                      bc, logits, n);

    maxpart<<<256, 256, 0, stream>>>(logits, n, pmax, denom);
    exp_kernel<<<nbN, 256, 0, stream>>>(logits, pmax, (float*)d_out, denom, n);
    norm_kernel<<<nbN, 256, 0, stream>>>((float*)d_out, denom, n);
}

// Round 9
// 244.257 us; speedup vs baseline: 1.2840x; 1.2840x over previous
//
#include <hip/hip_runtime.h>
#include <hip/hip_fp16.h>

// GCN: 2x (linear -> deg-normalized scatter-add -> bias -> tanh) -> linear(1) -> softmax(N)
// R8: revert R7's column split (VALU duplication > cache gain). R6 structure +
// epilogue de-dup: each lane handles only its 2 unique dims after the xor-reduce
// (2 tanh + 4B store vs 4x-redundant 8 tanh). Loop unchanged: 16 lanes/edge,
// 4 edges/iter, fma_mix accumulate. MFMA GEMM + bucket-sort CSR unchanged.

#define BSHIFT 9
#define BSPAN  512
#define PCHUNK 4096
#define LCAP   12288

typedef _Float16 half8 __attribute__((ext_vector_type(8)));
typedef float floatx4 __attribute__((ext_vector_type(4)));

__device__ inline void fmix2(float& a0, float& a1, unsigned int h2) {
    asm("v_fma_mix_f32 %0, %1, 1.0, %0 op_sel:[0,0,0] op_sel_hi:[1,0,0]" : "+v"(a0) : "v"(h2));
    asm("v_fma_mix_f32 %0, %1, 1.0, %0 op_sel:[1,0,0] op_sel_hi:[1,0,0]" : "+v"(a1) : "v"(h2));
}
__device__ inline void fmix_acc8(float* acc, uint4 v) {
    fmix2(acc[0], acc[1], v.x);
    fmix2(acc[2], acc[3], v.y);
    fmix2(acc[4], acc[5], v.z);
    fmix2(acc[6], acc[7], v.w);
}

// exact-saturating fast tanh: 1 - 2/(e^2x + 1)
__device__ inline float tanh_fast(float x) {
    float e = __expf(2.0f * x);
    return 1.0f - 2.0f * __builtin_amdgcn_rcpf(e + 1.0f);
}

// ---------------- CSR build (2-level bucket counting sort) ----------------
__global__ __launch_bounds__(256) void hist_buckets(const int* __restrict__ col, int E,
                                                    int* __restrict__ bucketCnt) {
    __shared__ int h[256];
    h[threadIdx.x] = 0;
    __syncthreads();
    for (int e = blockIdx.x * 256 + threadIdx.x; e < E; e += gridDim.x * 256)
        atomicAdd(&h[col[e] >> BSHIFT], 1);
    __syncthreads();
    int v = h[threadIdx.x];
    if (v) atomicAdd(&bucketCnt[threadIdx.x], v);
}

__global__ void scan_buckets(const int* __restrict__ cnt, int* __restrict__ bucketPtr,
                             int* __restrict__ cursor, int NB, int E) {
    __shared__ int s[256];
    int t = threadIdx.x;
    int v = (t < NB) ? cnt[t] : 0;
    s[t] = v;
    __syncthreads();
    for (int d = 1; d < 256; d <<= 1) {
        int x = (t >= d) ? s[t - d] : 0;
        __syncthreads();
        s[t] += x;
        __syncthreads();
    }
    if (t < NB) {
        int p = s[t] - v;
        bucketPtr[t] = p;
        cursor[t] = p;
    }
    if (t == 0) bucketPtr[NB] = E;
}

// pairs packed: (src << BSHIFT) | (dst & (BSPAN-1))   [src < 2^23]
__global__ __launch_bounds__(256) void partition_edges(const int* __restrict__ row,
                                                       const int* __restrict__ col, int E,
                                                       int* __restrict__ cursor,
                                                       unsigned int* __restrict__ pairs) {
    __shared__ int hist[256], sscan[256], gdelta[256], hcur[256];
    __shared__ uint2 stage[PCHUNK];
    int t = threadIdx.x;
    int base = blockIdx.x * PCHUNK;
    int cnt = min(PCHUNK, E - base);
    hist[t] = 0;
    __syncthreads();
    uint2 v[16];
    int b_[16];
#pragma unroll
    for (int k = 0; k < 16; k++) {
        int idx = t + k * 256;
        if (idx < cnt) {
            int c = col[base + idx], r = row[base + idx];
            v[k] = make_uint2((unsigned)c, (unsigned)r);
            b_[k] = c >> BSHIFT;
            atomicAdd(&hist[b_[k]], 1);
        } else b_[k] = -1;
    }
    __syncthreads();
    int hv = hist[t];
    sscan[t] = hv;
    __syncthreads();
    for (int d = 1; d < 256; d <<= 1) {
        int x = (t >= d) ? sscan[t - d] : 0;
        __syncthreads();
        sscan[t] += x;
        __syncthreads();
    }
    int excl = sscan[t] - hv;
    if (hv > 0) {
        int g = atomicAdd(&cursor[t], hv);
        gdelta[t] = g - excl;
    }
    hcur[t] = excl;
    __syncthreads();
#pragma unroll
    for (int k = 0; k < 16; k++) {
        if (b_[k] >= 0) {
            int slot = atomicAdd(&hcur[b_[k]], 1);
            stage[slot] = v[k];
        }
    }
    __syncthreads();
    for (int i = t; i < cnt; i += 256) {
        uint2 p = stage[i];
        pairs[gdelta[p.x >> BSHIFT] + i] = (p.y << BSHIFT) | (p.x & (BSPAN - 1));
    }
}

__global__ __launch_bounds__(256) void build_bucket_csr(const unsigned int* __restrict__ pairs,
                                                        const int* __restrict__ bucketPtr,
                                                        int* __restrict__ rowptr,
                                                        float* __restrict__ dinv,
                                                        int* __restrict__ csr,
                                                        int n, int NB, int E) {
    __shared__ int hist[BSPAN];
    __shared__ int lptr[BSPAN];
    __shared__ int s[256];
    __shared__ int srcStage[LCAP];
    int b = blockIdx.x, t = threadIdx.x;
    int base = bucketPtr[b], cnt = bucketPtr[b + 1] - base;
    int node0 = b << BSHIFT;
    int nn = min(BSPAN, n - node0);
    hist[t] = 0; hist[t + 256] = 0;
    __syncthreads();
    for (int i = t; i < cnt; i += 256)
        atomicAdd(&hist[pairs[base + i] & (BSPAN - 1)], 1);
    __syncthreads();
    int a0 = hist[2 * t], a1 = hist[2 * t + 1];
    int sum = a0 + a1;
    s[t] = sum;
    __syncthreads();
    for (int d = 1; d < 256; d <<= 1) {
        int x = (t >= d) ? s[t - d] : 0;
        __syncthreads();
        s[t] += x;
        __syncthreads();
    }
    int excl = s[t] - sum;
    lptr[2 * t] = excl;
    lptr[2 * t + 1] = excl + a0;
    __syncthreads();
    for (int lc = t; lc < nn; lc += 256) {
        rowptr[node0 + lc] = base + lptr[lc];
        dinv[node0 + lc] = rsqrtf((float)(hist[lc] + 1));
    }
    if (b == NB - 1 && t == 0) rowptr[n] = E;
    __syncthreads();
    hist[t] = 0; hist[t + 256] = 0;
    __syncthreads();
    bool inLds = (cnt <= LCAP);
    for (int i = t; i < cnt; i += 256) {
        unsigned int p = pairs[base + i];
        int lc = p & (BSPAN - 1);
        int rank = atomicAdd(&hist[lc], 1);
        int slot = lptr[lc] + rank;
        if (inLds) srcStage[slot] = (int)(p >> BSHIFT);
        else csr[base + slot] = (int)(p >> BSHIFT);
    }
    __syncthreads();
    if (inLds)
        for (int i = t; i < cnt; i += 256) csr[base + i] = srcStage[i];
}

// ---------------- W1,W2 -> B-fragment layout (fp16), one launch ----------------
__global__ __launch_bounds__(256) void prep_wfrags(const float* __restrict__ W1,
                                                   const float* __restrict__ W2,
                                                   uint4* __restrict__ F1,
                                                   uint4* __restrict__ F2) {
    int g = blockIdx.x * 256 + threadIdx.x;   // 0..4095
    const float* W = (g < 2048) ? W1 : W2;
    uint4* F = (g < 2048) ? F1 : F2;
    int t = g & 2047;
    int lane = t & 63, ct = (t >> 6) & 7, ks = t >> 9;
    int col = ct * 16 + (lane & 15);
    int kb = ks * 32 + (lane >> 4) * 8;
    half8 v;
#pragma unroll
    for (int j = 0; j < 8; j++) v[j] = (_Float16)W[(kb + j) * 128 + col];
    F[t] = __builtin_bit_cast(uint4, v);
}

// ---------------- MFMA GEMM: C[r,:] = fp16( dinv[r] * (A[r,:] @ W) ) ----------------
template <bool HALF_IN>
__global__ __launch_bounds__(256) void gemm_mfma(const void* __restrict__ Ap,
                                                 const uint4* __restrict__ F,
                                                 const float* __restrict__ dinv,
                                                 unsigned short* __restrict__ C, int n) {
    int w = threadIdx.x >> 6, lane = threadIdx.x & 63;
    int r0 = blockIdx.x * 128 + w * 32;
    int rA0 = r0 + (lane & 15);
    int rA1 = rA0 + 16;
    int kc = lane >> 4;
    floatx4 acc[2][8] = {};

#pragma unroll
    for (int ks = 0; ks < 4; ks++) {
        half8 a0 = {}, a1 = {};
        if constexpr (HALF_IN) {
            const uint4* A4 = (const uint4*)Ap;
            if (rA0 < n) a0 = __builtin_bit_cast(half8, A4[(size_t)rA0 * 16 + ks * 4 + kc]);
            if (rA1 < n) a1 = __builtin_bit_cast(half8, A4[(size_t)rA1 * 16 + ks * 4 + kc]);
        } else {
            const float* Af = (const float*)Ap;
            if (rA0 < n) {
                const float4* p = (const float4*)&Af[(size_t)rA0 * 128 + ks * 32 + kc * 8];
                float4 u = p[0], v = p[1];
                a0[0] = (_Float16)u.x; a0[1] = (_Float16)u.y; a0[2] = (_Float16)u.z; a0[3] = (_Float16)u.w;
                a0[4] = (_Float16)v.x; a0[5] = (_Float16)v.y; a0[6] = (_Float16)v.z; a0[7] = (_Float16)v.w;
            }
            if (rA1 < n) {
                const float4* p = (const float4*)&Af[(size_t)rA1 * 128 + ks * 32 + kc * 8];
                float4 u = p[0], v = p[1];
                a1[0] = (_Float16)u.x; a1[1] = (_Float16)u.y; a1[2] = (_Float16)u.z; a1[3] = (_Float16)u.w;
                a1[4] = (_Float16)v.x; a1[5] = (_Float16)v.y; a1[6] = (_Float16)v.z; a1[7] = (_Float16)v.w;
            }
        }
        half8 b[8];
#pragma unroll
        for (int ct = 0; ct < 8; ct++)
            b[ct] = __builtin_bit_cast(half8, F[ks * 512 + ct * 64 + lane]);
#pragma unroll
        for (int ct = 0; ct < 8; ct++) {
            acc[0][ct] = __builtin_amdgcn_mfma_f32_16x16x32_f16(a0, b[ct], acc[0][ct], 0, 0, 0);
            acc[1][ct] = __builtin_amdgcn_mfma_f32_16x16x32_f16(a1, b[ct], acc[1][ct], 0, 0, 0);
        }
    }

#pragma unroll
    for (int rt = 0; rt < 2; rt++) {
        int rbase = r0 + rt * 16 + (lane >> 4) * 4;
#pragma unroll
        for (int reg = 0; reg < 4; reg++) {
            int r = rbase + reg;
            if (r < n) {
                float di = dinv[r];
#pragma unroll
                for (int ct = 0; ct < 8; ct++) {
                    _Float16 h = (_Float16)(acc[rt][ct][reg] * di);
                    C[(size_t)r * 128 + ct * 16 + (lane & 15)] =
                        __builtin_bit_cast(unsigned short, h);
                }
            }
        }
    }
}

// ---------------- aggregation: wave/node, fma_mix loop, de-duplicated epilogue ----
// loop: 16 lanes/edge (uint4 = 8 fp16), 4 edges/iter. After xor-reduce every lane
// holds all 8 sums for dims m*8..m*8+7; lane (grp,m) finishes only dims m*8+2g,+2g+1.
__global__ __launch_bounds__(256) void aggregate(const uint4* __restrict__ T,
                                                 const int* __restrict__ csr,
                                                 const int* __restrict__ rowptr,
                                                 const float* __restrict__ dinv,
                                                 const float* __restrict__ bias,
                                                 unsigned int* __restrict__ Out, int n) {
    int node = (int)((blockIdx.x * 256 + threadIdx.x) >> 6);
    int lane = threadIdx.x & 63;
    if (node >= n) return;
    int grp = lane >> 4, m = lane & 15;

    float acc[8] = {};
    int beg = rowptr[node], end = rowptr[node + 1];
    int e = beg;
    while (e < end) {
        int take = min(end - e, 64);
        int myidx = (lane < take) ? csr[e + lane] : 0;
#pragma unroll 4
        for (int j = 0; j < take; j += 4) {
            int src = __shfl(myidx, j + grp);
            if (j + grp < take) {
                uint4 v = T[(size_t)src * 16 + m];
                fmix_acc8(acc, v);
            }
        }
        e += take;
    }
#pragma unroll
    for (int q = 0; q < 8; q++) {
        acc[q] += __shfl_xor(acc[q], 16);
        acc[q] += __shfl_xor(acc[q], 32);
    }

    // epilogue: this lane finishes dims m*8 + 2*grp, +1
    int u = m * 4 + grp;                       // uint (half2) index within the 64-uint row
    float a0 = acc[2 * grp], a1 = acc[2 * grp + 1];
    unsigned int self = ((const unsigned int*)T)[(size_t)node * 64 + u];
    fmix2(a0, a1, self);
    float di = dinv[node];
    float2 b = *(const float2*)&bias[m * 8 + 2 * grp];
    float o0 = tanh_fast(a0 * di + b.x);
    float o1 = tanh_fast(a1 * di + b.y);
    Out[(size_t)node * 64 + u] = __builtin_bit_cast(unsigned int, __floats2half2_rn(o0, o1));
}

// same, fused with classifier head: logits[node] = tanh(h)·Wc + bc
__global__ __launch_bounds__(256) void aggregate_logits(const uint4* __restrict__ T,
                                                        const int* __restrict__ csr,
                                                        const int* __restrict__ rowptr,
                                                        const float* __restrict__ dinv,
                                                        const float* __restrict__ bias,
                                                        const float* __restrict__ Wc,
                                                        const float* __restrict__ bc,
                                                        float* __restrict__ logits, int n) {
    int node = (int)((blockIdx.x * 256 + threadIdx.x) >> 6);
    int lane = threadIdx.x & 63;
    if (node >= n) return;
    int grp = lane >> 4, m = lane & 15;

    float acc[8] = {};
    int beg = rowptr[node], end = rowptr[node + 1];
    int e = beg;
    while (e < end) {
        int take = min(end - e, 64);
        int myidx = (lane < take) ? csr[e + lane] : 0;
#pragma unroll 4
        for (int j = 0; j < take; j += 4) {
            int src = __shfl(myidx, j + grp);
            if (j + grp < take) {
                uint4 v = T[(size_t)src * 16 + m];
                fmix_acc8(acc, v);
            }
        }
        e += take;
    }
#pragma unroll
    for (int q = 0; q < 8; q++) {
        acc[q] += __shfl_xor(acc[q], 16);
        acc[q] += __shfl_xor(acc[q], 32);
    }

    int u = m * 4 + grp;
    float a0 = acc[2 * grp], a1 = acc[2 * grp + 1];
    unsigned int self = ((const unsigned int*)T)[(size_t)node * 64 + u];
    fmix2(a0, a1, self);
    float di = dinv[node];
    float2 b = *(const float2*)&bias[m * 8 + 2 * grp];
    float2 w = *(const float2*)&Wc[m * 8 + 2 * grp];
    float d = tanh_fast(a0 * di + b.x) * w.x + tanh_fast(a1 * di + b.y) * w.y;
#pragma unroll
    for (int off = 1; off < 64; off <<= 1) d += __shfl_xor(d, off);
    if (lane == 0) logits[node] = d + bc[0];
}

// ---------------- softmax over N ----------------
__global__ __launch_bounds__(256) void maxpart(const float* __restrict__ logits, int n,
                                               float* __restrict__ partialMax,
                                               float* __restrict__ denom) {
    if (blockIdx.x == 0 && threadIdx.x == 0) *denom = 0.0f;
    __shared__ float s[256];
    float m = -3.4e38f;
    for (int i = blockIdx.x * 256 + threadIdx.x; i < n; i += 256 * 256)
        m = fmaxf(m, logits[i]);
    s[threadIdx.x] = m;
    __syncthreads();
    for (int d = 128; d; d >>= 1) {
        if (threadIdx.x < d) s[threadIdx.x] = fmaxf(s[threadIdx.x], s[threadIdx.x + d]);
        __syncthreads();
    }
    if (threadIdx.x == 0) partialMax[blockIdx.x] = s[0];
}

__global__ __launch_bounds__(256) void exp_kernel(const float* __restrict__ logits,
                                                  const float* __restrict__ partialMax,
                                                  float* __restrict__ outv,
                                                  float* __restrict__ denom, int n) {
    __shared__ float s[256];
    s[threadIdx.x] = partialMax[threadIdx.x];
    __syncthreads();
    for (int d = 128; d; d >>= 1) {
        if (threadIdx.x < d) s[threadIdx.x] = fmaxf(s[threadIdx.x], s[threadIdx.x + d]);
        __syncthreads();
    }
    float maxv = s[0];
    __syncthreads();
    int i = blockIdx.x * 256 + threadIdx.x;
    float e = 0.0f;
    if (i < n) {
        e = expf(logits[i] - maxv);
        outv[i] = e;
    }
    s[threadIdx.x] = e;
    __syncthreads();
    for (int d = 128; d; d >>= 1) {
        if (threadIdx.x < d) s[threadIdx.x] += s[threadIdx.x + d];
        __syncthreads();
    }
    if (threadIdx.x == 0) atomicAdd(denom, s[0]);
}

__global__ __launch_bounds__(256) void norm_kernel(float* __restrict__ out,
                                                   const float* __restrict__ denom, int n) {
    int i = blockIdx.x * 256 + threadIdx.x;
    if (i < n) out[i] = out[i] / (*denom);
}

extern "C" void kernel_launch(void* const* d_in, const int* in_sizes, int n_in,
                              void* d_out, int out_size, void* d_ws, size_t ws_size,
                              hipStream_t stream) {
    const float* x  = (const float*)d_in[0];
    const int*   ei = (const int*)d_in[1];   // [2,E] int32 (JAX x64 disabled)
    const float* W1 = (const float*)d_in[2];
    const float* b1 = (const float*)d_in[3];
    const float* W2 = (const float*)d_in[4];
    const float* b2 = (const float*)d_in[5];
    const float* Wc = (const float*)d_in[6];
    const float* bc = (const float*)d_in[7];

    int n = in_sizes[0] / 128;
    int E = in_sizes[1] / 2;
    const int* row = ei;
    const int* col = ei + E;
    int NB = (n + BSPAN - 1) >> BSHIFT;

    char* ws = (char*)d_ws;
    size_t off = 0;
    auto alloc = [&](size_t bytes) -> void* {
        void* p = ws + off;
        off += (bytes + 255) & ~(size_t)255;
        return p;
    };
    uint4*  A        = (uint4*)alloc((size_t)n * 128 * 2);
    uint4*  B        = (uint4*)alloc((size_t)n * 128 * 2);
    unsigned int* pairs = (unsigned int*)alloc((size_t)E * 4);
    int*    csr      = (int*)alloc((size_t)E * 4);
    float*  dinv     = (float*)alloc((size_t)n * 4);
    int*    rowptr   = (int*)alloc((size_t)(n + 1) * 4);
    int*    bucketCnt= (int*)alloc(256 * 4);
    int*    bucketPtr= (int*)alloc(257 * 4);
    int*    cursor   = (int*)alloc(256 * 4);
    uint4*  F1       = (uint4*)alloc(2048 * 16);
    uint4*  F2       = (uint4*)alloc(2048 * 16);
    float*  logits   = (float*)alloc((size_t)n * 4);
    float*  pmax     = (float*)alloc(256 * 4);
    float*  denom    = (float*)alloc(4);

    int nbN = (n + 255) / 256;
    int nbW = (n + 3) / 4;
    int nbG = (n + 127) / 128;

    hipMemsetAsync(bucketCnt, 0, 256 * 4, stream);

    hist_buckets<<<512, 256, 0, stream>>>(col, E, bucketCnt);
    scan_buckets<<<1, 256, 0, stream>>>(bucketCnt, bucketPtr, cursor, NB, E);
    partition_edges<<<(E + PCHUNK - 1) / PCHUNK, 256, 0, stream>>>(row, col, E, cursor, pairs);
    prep_wfrags<<<16, 256, 0, stream>>>(W1, W2, F1, F2);
    build_bucket_csr<<<NB, 256, 0, stream>>>(pairs, bucketPtr, rowptr, dinv, csr, n, NB, E);

    gemm_mfma<false><<<nbG, 256, 0, stream>>>(x, F1, dinv, (unsigned short*)A, n);
    aggregate<<<nbW, 256, 0, stream>>>(A, csr, rowptr, dinv, b1, (unsigned int*)B, n);
    gemm_mfma<true><<<nbG, 256, 0, stream>>>(B, F2, dinv, (unsigned short*)A, n);
    aggregate_logits<<<nbW, 256, 0, stream>>>(A, csr, rowptr, dinv, b2, Wc, bc, logits, n);

    maxpart<<<256, 256, 0, stream>>>(logits, n, pmax, denom);
    exp_kernel<<<nbN, 256, 0, stream>>>(logits, pmax, (float*)d_out, denom, n);
    norm_kernel<<<nbN, 256, 0, stream>>>((float*)d_out, denom, n);
}

// Round 10
// 235.004 us; speedup vs baseline: 1.3346x; 1.0394x over previous
//
#include <hip/hip_runtime.h>
#include <hip/hip_fp16.h>

// GCN: 2x (linear -> deg-normalized scatter-add -> bias -> tanh) -> linear(1) -> softmax(N)
// R9: gathered feature matrices (T1, T2) stored fp8 e4m3 (128B/row) -> halves the
// random-gather bytes (the measured ~3.5 TB/s fetch-path is the wall). Dense
// intermediates stay fp16/fp32; GEMM stays f16 MFMA. GEMM epilogue packs 8 cols
// per thread into 2 dwords => fixed column permutation p=(c&15)*8+(c>>4), absorbed
// by permuted bias/Wc reads, permuted h1 layout, and W2 row-perm in prep_wfrags.

#define BSHIFT 9
#define BSPAN  512
#define PCHUNK 4096
#define LCAP   12288

typedef _Float16 half8 __attribute__((ext_vector_type(8)));
typedef float floatx4 __attribute__((ext_vector_type(4)));
typedef float floatx2 __attribute__((ext_vector_type(2)));

// exact-saturating fast tanh: 1 - 2/(e^2x + 1)
__device__ inline float tanh_fast(float x) {
    float e = __expf(2.0f * x);
    return 1.0f - 2.0f * __builtin_amdgcn_rcpf(e + 1.0f);
}

// accumulate 16 fp8 (one uint4) into acc[8] of float2
__device__ inline void fp8_acc16(floatx2* acc, uint4 v) {
    acc[0] += __builtin_amdgcn_cvt_pk_f32_fp8((int)v.x, false);
    acc[1] += __builtin_amdgcn_cvt_pk_f32_fp8((int)v.x, true);
    acc[2] += __builtin_amdgcn_cvt_pk_f32_fp8((int)v.y, false);
    acc[3] += __builtin_amdgcn_cvt_pk_f32_fp8((int)v.y, true);
    acc[4] += __builtin_amdgcn_cvt_pk_f32_fp8((int)v.z, false);
    acc[5] += __builtin_amdgcn_cvt_pk_f32_fp8((int)v.z, true);
    acc[6] += __builtin_amdgcn_cvt_pk_f32_fp8((int)v.w, false);
    acc[7] += __builtin_amdgcn_cvt_pk_f32_fp8((int)v.w, true);
}

// ---------------- CSR build (2-level bucket counting sort) ----------------
__global__ __launch_bounds__(256) void hist_buckets(const int* __restrict__ col, int E,
                                                    int* __restrict__ bucketCnt) {
    __shared__ int h[256];
    h[threadIdx.x] = 0;
    __syncthreads();
    for (int e = blockIdx.x * 256 + threadIdx.x; e < E; e += gridDim.x * 256)
        atomicAdd(&h[col[e] >> BSHIFT], 1);
    __syncthreads();
    int v = h[threadIdx.x];
    if (v) atomicAdd(&bucketCnt[threadIdx.x], v);
}

__global__ void scan_buckets(const int* __restrict__ cnt, int* __restrict__ bucketPtr,
                             int* __restrict__ cursor, int NB, int E) {
    __shared__ int s[256];
    int t = threadIdx.x;
    int v = (t < NB) ? cnt[t] : 0;
    s[t] = v;
    __syncthreads();
    for (int d = 1; d < 256; d <<= 1) {
        int x = (t >= d) ? s[t - d] : 0;
        __syncthreads();
        s[t] += x;
        __syncthreads();
    }
    if (t < NB) {
        int p = s[t] - v;
        bucketPtr[t] = p;
        cursor[t] = p;
    }
    if (t == 0) bucketPtr[NB] = E;
}

// pairs packed: (src << BSHIFT) | (dst & (BSPAN-1))   [src < 2^23]
__global__ __launch_bounds__(256) void partition_edges(const int* __restrict__ row,
                                                       const int* __restrict__ col, int E,
                                                       int* __restrict__ cursor,
                                                       unsigned int* __restrict__ pairs) {
    __shared__ int hist[256], sscan[256], gdelta[256], hcur[256];
    __shared__ uint2 stage[PCHUNK];
    int t = threadIdx.x;
    int base = blockIdx.x * PCHUNK;
    int cnt = min(PCHUNK, E - base);
    hist[t] = 0;
    __syncthreads();
    uint2 v[16];
    int b_[16];
#pragma unroll
    for (int k = 0; k < 16; k++) {
        int idx = t + k * 256;
        if (idx < cnt) {
            int c = col[base + idx], r = row[base + idx];
            v[k] = make_uint2((unsigned)c, (unsigned)r);
            b_[k] = c >> BSHIFT;
            atomicAdd(&hist[b_[k]], 1);
        } else b_[k] = -1;
    }
    __syncthreads();
    int hv = hist[t];
    sscan[t] = hv;
    __syncthreads();
    for (int d = 1; d < 256; d <<= 1) {
        int x = (t >= d) ? sscan[t - d] : 0;
        __syncthreads();
        sscan[t] += x;
        __syncthreads();
    }
    int excl = sscan[t] - hv;
    if (hv > 0) {
        int g = atomicAdd(&cursor[t], hv);
        gdelta[t] = g - excl;
    }
    hcur[t] = excl;
    __syncthreads();
#pragma unroll
    for (int k = 0; k < 16; k++) {
        if (b_[k] >= 0) {
            int slot = atomicAdd(&hcur[b_[k]], 1);
            stage[slot] = v[k];
        }
    }
    __syncthreads();
    for (int i = t; i < cnt; i += 256) {
        uint2 p = stage[i];
        pairs[gdelta[p.x >> BSHIFT] + i] = (p.y << BSHIFT) | (p.x & (BSPAN - 1));
    }
}

__global__ __launch_bounds__(256) void build_bucket_csr(const unsigned int* __restrict__ pairs,
                                                        const int* __restrict__ bucketPtr,
                                                        int* __restrict__ rowptr,
                                                        float* __restrict__ dinv,
                                                        int* __restrict__ csr,
                                                        int n, int NB, int E) {
    __shared__ int hist[BSPAN];
    __shared__ int lptr[BSPAN];
    __shared__ int s[256];
    __shared__ int srcStage[LCAP];
    int b = blockIdx.x, t = threadIdx.x;
    int base = bucketPtr[b], cnt = bucketPtr[b + 1] - base;
    int node0 = b << BSHIFT;
    int nn = min(BSPAN, n - node0);
    hist[t] = 0; hist[t + 256] = 0;
    __syncthreads();
    for (int i = t; i < cnt; i += 256)
        atomicAdd(&hist[pairs[base + i] & (BSPAN - 1)], 1);
    __syncthreads();
    int a0 = hist[2 * t], a1 = hist[2 * t + 1];
    int sum = a0 + a1;
    s[t] = sum;
    __syncthreads();
    for (int d = 1; d < 256; d <<= 1) {
        int x = (t >= d) ? s[t - d] : 0;
        __syncthreads();
        s[t] += x;
        __syncthreads();
    }
    int excl = s[t] - sum;
    lptr[2 * t] = excl;
    lptr[2 * t + 1] = excl + a0;
    __syncthreads();
    for (int lc = t; lc < nn; lc += 256) {
        rowptr[node0 + lc] = base + lptr[lc];
        dinv[node0 + lc] = rsqrtf((float)(hist[lc] + 1));
    }
    if (b == NB - 1 && t == 0) rowptr[n] = E;
    __syncthreads();
    hist[t] = 0; hist[t + 256] = 0;
    __syncthreads();
    bool inLds = (cnt <= LCAP);
    for (int i = t; i < cnt; i += 256) {
        unsigned int p = pairs[base + i];
        int lc = p & (BSPAN - 1);
        int rank = atomicAdd(&hist[lc], 1);
        int slot = lptr[lc] + rank;
        if (inLds) srcStage[slot] = (int)(p >> BSHIFT);
        else csr[base + slot] = (int)(p >> BSHIFT);
    }
    __syncthreads();
    if (inLds)
        for (int i = t; i < cnt; i += 256) csr[base + i] = srcStage[i];
}

// ---------------- W1,W2 -> B-fragment layout (fp16), one launch ----------------
// F2 rows are permuted: gemm2's K-dim is the permuted h1 layout, so
// frag row k reads W2[dim(k)] with dim(k) = ((k&7)<<4) | (k>>3).
__global__ __launch_bounds__(256) void prep_wfrags(const float* __restrict__ W1,
                                                   const float* __restrict__ W2,
                                                   uint4* __restrict__ F1,
                                                   uint4* __restrict__ F2) {
    int g = blockIdx.x * 256 + threadIdx.x;   // 0..4095
    bool second = (g >= 2048);
    const float* W = second ? W2 : W1;
    uint4* F = second ? F2 : F1;
    int t = g & 2047;
    int lane = t & 63, ct = (t >> 6) & 7, ks = t >> 9;
    int col = ct * 16 + (lane & 15);
    int kb = ks * 32 + (lane >> 4) * 8;
    half8 v;
#pragma unroll
    for (int j = 0; j < 8; j++) {
        int k = kb + j;
        int krow = second ? (((k & 7) << 4) | (k >> 3)) : k;
        v[j] = (_Float16)W[krow * 128 + col];
    }
    F[t] = __builtin_bit_cast(uint4, v);
}

// ---------------- MFMA GEMM: T8[r, p] = fp8( dinv[r] * (A[r,:] @ W) ), permuted p ----
// Epilogue: thread c=lane&15 owns output cols ct*16+c (ct=0..7), packed into bytes
// c*8+ct of the row => byte p holds col ((p&7)<<4)|(p>>3).
template <bool HALF_IN>
__global__ __launch_bounds__(256) void gemm_mfma(const void* __restrict__ Ap,
                                                 const uint4* __restrict__ F,
                                                 const float* __restrict__ dinv,
                                                 unsigned char* __restrict__ T8, int n) {
    int w = threadIdx.x >> 6, lane = threadIdx.x & 63;
    int r0 = blockIdx.x * 128 + w * 32;
    int rA0 = r0 + (lane & 15);
    int rA1 = rA0 + 16;
    int kc = lane >> 4;
    floatx4 acc[2][8] = {};

#pragma unroll
    for (int ks = 0; ks < 4; ks++) {
        half8 a0 = {}, a1 = {};
        if constexpr (HALF_IN) {
            const uint4* A4 = (const uint4*)Ap;
            if (rA0 < n) a0 = __builtin_bit_cast(half8, A4[(size_t)rA0 * 16 + ks * 4 + kc]);
            if (rA1 < n) a1 = __builtin_bit_cast(half8, A4[(size_t)rA1 * 16 + ks * 4 + kc]);
        } else {
            const float* Af = (const float*)Ap;
            if (rA0 < n) {
                const float4* p = (const float4*)&Af[(size_t)rA0 * 128 + ks * 32 + kc * 8];
                float4 u = p[0], v = p[1];
                a0[0] = (_Float16)u.x; a0[1] = (_Float16)u.y; a0[2] = (_Float16)u.z; a0[3] = (_Float16)u.w;
                a0[4] = (_Float16)v.x; a0[5] = (_Float16)v.y; a0[6] = (_Float16)v.z; a0[7] = (_Float16)v.w;
            }
            if (rA1 < n) {
                const float4* p = (const float4*)&Af[(size_t)rA1 * 128 + ks * 32 + kc * 8];
                float4 u = p[0], v = p[1];
                a1[0] = (_Float16)u.x; a1[1] = (_Float16)u.y; a1[2] = (_Float16)u.z; a1[3] = (_Float16)u.w;
                a1[4] = (_Float16)v.x; a1[5] = (_Float16)v.y; a1[6] = (_Float16)v.z; a1[7] = (_Float16)v.w;
            }
        }
        half8 b[8];
#pragma unroll
        for (int ct = 0; ct < 8; ct++)
            b[ct] = __builtin_bit_cast(half8, F[ks * 512 + ct * 64 + lane]);
#pragma unroll
        for (int ct = 0; ct < 8; ct++) {
            acc[0][ct] = __builtin_amdgcn_mfma_f32_16x16x32_f16(a0, b[ct], acc[0][ct], 0, 0, 0);
            acc[1][ct] = __builtin_amdgcn_mfma_f32_16x16x32_f16(a1, b[ct], acc[1][ct], 0, 0, 0);
        }
    }

    int c = lane & 15;
#pragma unroll
    for (int rt = 0; rt < 2; rt++) {
        int rbase = r0 + rt * 16 + (lane >> 4) * 4;
#pragma unroll
        for (int reg = 0; reg < 4; reg++) {
            int r = rbase + reg;
            if (r < n) {
                float di = dinv[r];
                float vv[8];
#pragma unroll
                for (int ct = 0; ct < 8; ct++) vv[ct] = acc[rt][ct][reg] * di;
                int d0 = __builtin_amdgcn_cvt_pk_fp8_f32(vv[0], vv[1], 0, false);
                d0 = __builtin_amdgcn_cvt_pk_fp8_f32(vv[2], vv[3], d0, true);
                int d1 = __builtin_amdgcn_cvt_pk_fp8_f32(vv[4], vv[5], 0, false);
                d1 = __builtin_amdgcn_cvt_pk_fp8_f32(vv[6], vv[7], d1, true);
                *(uint2*)(T8 + (size_t)r * 128 + c * 8) = make_uint2((unsigned)d0, (unsigned)d1);
            }
        }
    }
}

// ---------------- aggregation: wave/node over fp8 rows ----------------
// 8 lanes/edge (uint4 = 16 fp8), 8 edges/iter. Lane (grp=lane>>3, m=lane&7) holds
// chunk m (bytes m*16..+15); after xor-reduce finishes byte-pair q=m*16+2*grp.
// Original dim of byte q: dim(q) = ((q&7)<<4)|(q>>3); dim(q+1) = dim(q)+16.
__global__ __launch_bounds__(256) void aggregate(const unsigned char* __restrict__ T8,
                                                 const int* __restrict__ csr,
                                                 const int* __restrict__ rowptr,
                                                 const float* __restrict__ dinv,
                                                 const float* __restrict__ bias,
                                                 unsigned int* __restrict__ Out, int n) {
    int node = (int)((blockIdx.x * 256 + threadIdx.x) >> 6);
    int lane = threadIdx.x & 63;
    if (node >= n) return;
    int grp = lane >> 3, m = lane & 7;
    const uint4* T4 = (const uint4*)T8;

    floatx2 acc[8] = {};
    int beg = rowptr[node], end = rowptr[node + 1];
    int e = beg;
    while (e < end) {
        int take = min(end - e, 64);
        int myidx = (lane < take) ? csr[e + lane] : 0;
#pragma unroll 2
        for (int j = 0; j < take; j += 8) {
            int src = __shfl(myidx, j + grp);
            if (j + grp < take) fp8_acc16(acc, T4[(size_t)src * 8 + m]);
        }
        e += take;
    }
    float* af = (float*)acc;
#pragma unroll
    for (int q = 0; q < 16; q++) {
        af[q] += __shfl_xor(af[q], 8);
        af[q] += __shfl_xor(af[q], 16);
        af[q] += __shfl_xor(af[q], 32);
    }

    // epilogue: byte-pair q = m*16 + 2*grp -> acc slot grp
    int q = m * 16 + 2 * grp;
    int dim = ((q & 7) << 4) | (q >> 3);
    unsigned short us = *(const unsigned short*)(T8 + (size_t)node * 128 + q);
    floatx2 self = __builtin_amdgcn_cvt_pk_f32_fp8((int)us, false);
    float a0 = acc[grp].x + self.x, a1 = acc[grp].y + self.y;
    float di = dinv[node];
    float b0 = bias[dim], b1 = bias[dim + 16];
    float o0 = tanh_fast(a0 * di + b0);
    float o1 = tanh_fast(a1 * di + b1);
    Out[(size_t)node * 64 + (q >> 1)] =
        __builtin_bit_cast(unsigned int, __floats2half2_rn(o0, o1));
}

// same, fused with classifier head: logits[node] = tanh(h)·Wc + bc
__global__ __launch_bounds__(256) void aggregate_logits(const unsigned char* __restrict__ T8,
                                                        const int* __restrict__ csr,
                                                        const int* __restrict__ rowptr,
                                                        const float* __restrict__ dinv,
                                                        const float* __restrict__ bias,
                                                        const float* __restrict__ Wc,
                                                        const float* __restrict__ bc,
                                                        float* __restrict__ logits, int n) {
    int node = (int)((blockIdx.x * 256 + threadIdx.x) >> 6);
    int lane = threadIdx.x & 63;
    if (node >= n) return;
    int grp = lane >> 3, m = lane & 7;
    const uint4* T4 = (const uint4*)T8;

    floatx2 acc[8] = {};
    int beg = rowptr[node], end = rowptr[node + 1];
    int e = beg;
    while (e < end) {
        int take = min(end - e, 64);
        int myidx = (lane < take) ? csr[e + lane] : 0;
#pragma unroll 2
        for (int j = 0; j < take; j += 8) {
            int src = __shfl(myidx, j + grp);
            if (j + grp < take) fp8_acc16(acc, T4[(size_t)src * 8 + m]);
        }
        e += take;
    }
    float* af = (float*)acc;
#pragma unroll
    for (int q = 0; q < 16; q++) {
        af[q] += __shfl_xor(af[q], 8);
        af[q] += __shfl_xor(af[q], 16);
        af[q] += __shfl_xor(af[q], 32);
    }

    int q = m * 16 + 2 * grp;
    int dim = ((q & 7) << 4) | (q >> 3);
    unsigned short us = *(const unsigned short*)(T8 + (size_t)node * 128 + q);
    floatx2 self = __builtin_amdgcn_cvt_pk_f32_fp8((int)us, false);
    float a0 = acc[grp].x + self.x, a1 = acc[grp].y + self.y;
    float di = dinv[node];
    float b0 = bias[dim], b1 = bias[dim + 16];
    float w0 = Wc[dim], w1 = Wc[dim + 16];
    float d = tanh_fast(a0 * di + b0) * w0 + tanh_fast(a1 * di + b1) * w1;
#pragma unroll
    for (int off = 1; off < 64; off <<= 1) d += __shfl_xor(d, off);
    if (lane == 0) logits[node] = d + bc[0];
}

// ---------------- softmax over N ----------------
__global__ __launch_bounds__(256) void maxpart(const float* __restrict__ logits, int n,
                                               float* __restrict__ partialMax,
                                               float* __restrict__ denom) {
    if (blockIdx.x == 0 && threadIdx.x == 0) *denom = 0.0f;
    __shared__ float s[256];
    float m = -3.4e38f;
    for (int i = blockIdx.x * 256 + threadIdx.x; i < n; i += 256 * 256)
        m = fmaxf(m, logits[i]);
    s[threadIdx.x] = m;
    __syncthreads();
    for (int d = 128; d; d >>= 1) {
        if (threadIdx.x < d) s[threadIdx.x] = fmaxf(s[threadIdx.x], s[threadIdx.x + d]);
        __syncthreads();
    }
    if (threadIdx.x == 0) partialMax[blockIdx.x] = s[0];
}

__global__ __launch_bounds__(256) void exp_kernel(const float* __restrict__ logits,
                                                  const float* __restrict__ partialMax,
                                                  float* __restrict__ outv,
                                                  float* __restrict__ denom, int n) {
    __shared__ float s[256];
    s[threadIdx.x] = partialMax[threadIdx.x];
    __syncthreads();
    for (int d = 128; d; d >>= 1) {
        if (threadIdx.x < d) s[threadIdx.x] = fmaxf(s[threadIdx.x], s[threadIdx.x + d]);
        __syncthreads();
    }
    float maxv = s[0];
    __syncthreads();
    int i = blockIdx.x * 256 + threadIdx.x;
    float e = 0.0f;
    if (i < n) {
        e = expf(logits[i] - maxv);
        outv[i] = e;
    }
    s[threadIdx.x] = e;
    __syncthreads();
    for (int d = 128; d; d >>= 1) {
        if (threadIdx.x < d) s[threadIdx.x] += s[threadIdx.x + d];
        __syncthreads();
    }
    if (threadIdx.x == 0) atomicAdd(denom, s[0]);
}

__global__ __launch_bounds__(256) void norm_kernel(float* __restrict__ out,
                                                   const float* __restrict__ denom, int n) {
    int i = blockIdx.x * 256 + threadIdx.x;
    if (i < n) out[i] = out[i] / (*denom);
}

extern "C" void kernel_launch(void* const* d_in, const int* in_sizes, int n_in,
                              void* d_out, int out_size, void* d_ws, size_t ws_size,
                              hipStream_t stream) {
    const float* x  = (const float*)d_in[0];
    const int*   ei = (const int*)d_in[1];   // [2,E] int32 (JAX x64 disabled)
    const float* W1 = (const float*)d_in[2];
    const float* b1 = (const float*)d_in[3];
    const float* W2 = (const float*)d_in[4];
    const float* b2 = (const float*)d_in[5];
    const float* Wc = (const float*)d_in[6];
    const float* bc = (const float*)d_in[7];

    int n = in_sizes[0] / 128;
    int E = in_sizes[1] / 2;
    const int* row = ei;
    const int* col = ei + E;
    int NB = (n + BSPAN - 1) >> BSHIFT;

    char* ws = (char*)d_ws;
    size_t off = 0;
    auto alloc = [&](size_t bytes) -> void* {
        void* p = ws + off;
        off += (bytes + 255) & ~(size_t)255;
        return p;
    };
    unsigned char* T1 = (unsigned char*)alloc((size_t)n * 128);      // fp8 gathered feats
    unsigned char* T2 = (unsigned char*)alloc((size_t)n * 128);      // fp8 gathered feats
    unsigned int*  H1 = (unsigned int*)alloc((size_t)n * 128 * 2);   // fp16 h1 (permuted)
    unsigned int* pairs = (unsigned int*)alloc((size_t)E * 4);
    int*    csr      = (int*)alloc((size_t)E * 4);
    float*  dinv     = (float*)alloc((size_t)n * 4);
    int*    rowptr   = (int*)alloc((size_t)(n + 1) * 4);
    int*    bucketCnt= (int*)alloc(256 * 4);
    int*    bucketPtr= (int*)alloc(257 * 4);
    int*    cursor   = (int*)alloc(256 * 4);
    uint4*  F1       = (uint4*)alloc(2048 * 16);
    uint4*  F2       = (uint4*)alloc(2048 * 16);
    float*  logits   = (float*)alloc((size_t)n * 4);
    float*  pmax     = (float*)alloc(256 * 4);
    float*  denom    = (float*)alloc(4);

    int nbN = (n + 255) / 256;
    int nbW = (n + 3) / 4;
    int nbG = (n + 127) / 128;

    hipMemsetAsync(bucketCnt, 0, 256 * 4, stream);

    hist_buckets<<<512, 256, 0, stream>>>(col, E, bucketCnt);
    scan_buckets<<<1, 256, 0, stream>>>(bucketCnt, bucketPtr, cursor, NB, E);
    partition_edges<<<(E + PCHUNK - 1) / PCHUNK, 256, 0, stream>>>(row, col, E, cursor, pairs);
    prep_wfrags<<<16, 256, 0, stream>>>(W1, W2, F1, F2);
    build_bucket_csr<<<NB, 256, 0, stream>>>(pairs, bucketPtr, rowptr, dinv, csr, n, NB, E);

    gemm_mfma<false><<<nbG, 256, 0, stream>>>(x, F1, dinv, T1, n);
    aggregate<<<nbW, 256, 0, stream>>>(T1, csr, rowptr, dinv, b1, H1, n);
    gemm_mfma<true><<<nbG, 256, 0, stream>>>(H1, F2, dinv, T2, n);
    aggregate_logits<<<nbW, 256, 0, stream>>>(T2, csr, rowptr, dinv, b2, Wc, bc, logits, n);

    maxpart<<<256, 256, 0, stream>>>(logits, n, pmax, denom);
    exp_kernel<<<nbN, 256, 0, stream>>>(logits, pmax, (float*)d_out, denom, n);
    norm_kernel<<<nbN, 256, 0, stream>>>((float*)d_out, denom, n);
}

// Round 12
// 218.510 us; speedup vs baseline: 1.4353x; 1.0755x over previous
//
#include <hip/hip_runtime.h>
#include <hip/hip_fp16.h>

// GCN: 2x (linear -> deg-normalized scatter-add -> bias -> tanh) -> linear(1) -> softmax(N)
// R11 = R10 + crash fix: padded CSR needs an explicit per-node END pointer
// (rowEndP) — rowptrP[node+1] crosses the inter-bucket gap (uninitialized ws)
// for the last node of each bucket, which fed garbage src indices -> fault.
// R10 features kept: fp8 gather, padded branchless loop (self-loop as edge,
// dummies -> zero row n), 32-bit offsets, uint2/lane + 16-bperm reduce.

#define BSHIFT 9
#define BSPAN  512
#define PCHUNK 4096
#define LCAP   12288
#define BPAD   2048   // max padding per bucket: 512 nodes * 4

typedef _Float16 half8 __attribute__((ext_vector_type(8)));
typedef float floatx4 __attribute__((ext_vector_type(4)));
typedef float floatx2 __attribute__((ext_vector_type(2)));

// exact-saturating fast tanh: 1 - 2/(e^2x + 1)
__device__ inline float tanh_fast(float x) {
    float e = __expf(2.0f * x);
    return 1.0f - 2.0f * __builtin_amdgcn_rcpf(e + 1.0f);
}

// accumulate 8 fp8 (one uint2) into 4 packed-f32 accumulators
__device__ inline void fp8_acc8(floatx2* acc, uint2 v) {
    acc[0] += __builtin_amdgcn_cvt_pk_f32_fp8((int)v.x, false);
    acc[1] += __builtin_amdgcn_cvt_pk_f32_fp8((int)v.x, true);
    acc[2] += __builtin_amdgcn_cvt_pk_f32_fp8((int)v.y, false);
    acc[3] += __builtin_amdgcn_cvt_pk_f32_fp8((int)v.y, true);
}

// ---------------- CSR build (2-level bucket counting sort) ----------------
__global__ __launch_bounds__(256) void hist_buckets(const int* __restrict__ col, int E,
                                                    int* __restrict__ bucketCnt) {
    __shared__ int h[256];
    h[threadIdx.x] = 0;
    __syncthreads();
    for (int e = blockIdx.x * 256 + threadIdx.x; e < E; e += gridDim.x * 256)
        atomicAdd(&h[col[e] >> BSHIFT], 1);
    __syncthreads();
    int v = h[threadIdx.x];
    if (v) atomicAdd(&bucketCnt[threadIdx.x], v);
}

__global__ void scan_buckets(const int* __restrict__ cnt, int* __restrict__ bucketPtr,
                             int* __restrict__ cursor, int NB, int E) {
    __shared__ int s[256];
    int t = threadIdx.x;
    int v = (t < NB) ? cnt[t] : 0;
    s[t] = v;
    __syncthreads();
    for (int d = 1; d < 256; d <<= 1) {
        int x = (t >= d) ? s[t - d] : 0;
        __syncthreads();
        s[t] += x;
        __syncthreads();
    }
    if (t < NB) {
        int p = s[t] - v;
        bucketPtr[t] = p;
        cursor[t] = p;
    }
    if (t == 0) bucketPtr[NB] = E;
}

// pairs packed: (src << BSHIFT) | (dst & (BSPAN-1))   [src < 2^23]
__global__ __launch_bounds__(256) void partition_edges(const int* __restrict__ row,
                                                       const int* __restrict__ col, int E,
                                                       int* __restrict__ cursor,
                                                       unsigned int* __restrict__ pairs) {
    __shared__ int hist[256], sscan[256], gdelta[256], hcur[256];
    __shared__ uint2 stage[PCHUNK];
    int t = threadIdx.x;
    int base = blockIdx.x * PCHUNK;
    int cnt = min(PCHUNK, E - base);
    hist[t] = 0;
    __syncthreads();
    uint2 v[16];
    int b_[16];
#pragma unroll
    for (int k = 0; k < 16; k++) {
        int idx = t + k * 256;
        if (idx < cnt) {
            int c = col[base + idx], r = row[base + idx];
            v[k] = make_uint2((unsigned)c, (unsigned)r);
            b_[k] = c >> BSHIFT;
            atomicAdd(&hist[b_[k]], 1);
        } else b_[k] = -1;
    }
    __syncthreads();
    int hv = hist[t];
    sscan[t] = hv;
    __syncthreads();
    for (int d = 1; d < 256; d <<= 1) {
        int x = (t >= d) ? sscan[t - d] : 0;
        __syncthreads();
        sscan[t] += x;
        __syncthreads();
    }
    int excl = sscan[t] - hv;
    if (hv > 0) {
        int g = atomicAdd(&cursor[t], hv);
        gdelta[t] = g - excl;
    }
    hcur[t] = excl;
    __syncthreads();
#pragma unroll
    for (int k = 0; k < 16; k++) {
        if (b_[k] >= 0) {
            int slot = atomicAdd(&hcur[b_[k]], 1);
            stage[slot] = v[k];
        }
    }
    __syncthreads();
    for (int i = t; i < cnt; i += 256) {
        uint2 p = stage[i];
        pairs[gdelta[p.x >> BSHIFT] + i] = (p.y << BSHIFT) | (p.x & (BSPAN - 1));
    }
}

// ---- per bucket: padded CSR. Self-loop at slot 0; padding -> zero row (index n).
// Emits rowptrP (start) AND rowEndP (start + paddedDeg) — ends never cross gaps. ----
__global__ __launch_bounds__(256) void build_bucket_csr(const unsigned int* __restrict__ pairs,
                                                        const int* __restrict__ bucketPtr,
                                                        int* __restrict__ rowptrP,
                                                        int* __restrict__ rowEndP,
                                                        float* __restrict__ dinv,
                                                        int* __restrict__ csrP,
                                                        int n, int NB, int E) {
    __shared__ int hist[BSPAN];
    __shared__ int lptr[BSPAN];
    __shared__ int s[256];
    __shared__ int srcStage[LCAP];
    __shared__ int totp;
    int b = blockIdx.x, t = threadIdx.x;
    int base = bucketPtr[b], cnt = bucketPtr[b + 1] - base;
    int baseP = base + b * BPAD;
    int node0 = b << BSHIFT;
    int nn = min(BSPAN, n - node0);
    hist[t] = 0; hist[t + 256] = 0;
    __syncthreads();
    for (int i = t; i < cnt; i += 256)
        atomicAdd(&hist[pairs[base + i] & (BSPAN - 1)], 1);
    __syncthreads();
    // padded degrees (deg + 1 self, rounded up to 4); phantom nodes get 0
    int d0 = (2 * t < nn)     ? ((hist[2 * t] + 4) & ~3)     : 0;
    int d1 = (2 * t + 1 < nn) ? ((hist[2 * t + 1] + 4) & ~3) : 0;
    int sum = d0 + d1;
    s[t] = sum;
    __syncthreads();
    for (int d = 1; d < 256; d <<= 1) {
        int x = (t >= d) ? s[t - d] : 0;
        __syncthreads();
        s[t] += x;
        __syncthreads();
    }
    int excl = s[t] - sum;
    lptr[2 * t] = excl;
    lptr[2 * t + 1] = excl + d0;
    if (t == 255) totp = s[255];
    __syncthreads();
    int cntp = totp;
    for (int lc = t; lc < nn; lc += 256) {
        int st = baseP + lptr[lc];
        int dP = (hist[lc] + 4) & ~3;
        rowptrP[node0 + lc] = st;
        rowEndP[node0 + lc] = st + dP;
        dinv[node0 + lc] = rsqrtf((float)(hist[lc] + 1));
    }
    __syncthreads();
    bool inLds = (cntp <= LCAP);
    if (inLds) {
        for (int i = t; i < cntp; i += 256) srcStage[i] = n;          // zero-row pad
        __syncthreads();
        for (int lc = t; lc < nn; lc += 256) srcStage[lptr[lc]] = node0 + lc;  // self
        hist[t] = 1; hist[t + 256] = 1;                               // cursors (after self)
        __syncthreads();
        for (int i = t; i < cnt; i += 256) {
            unsigned int p = pairs[base + i];
            int lc = p & (BSPAN - 1);
            int rank = atomicAdd(&hist[lc], 1);
            srcStage[lptr[lc] + rank] = (int)(p >> BSHIFT);
        }
        __syncthreads();
        for (int i = t; i < cntp; i += 256) csrP[baseP + i] = srcStage[i];
    } else {   // rare fallback: direct global
        for (int i = t; i < cntp; i += 256) csrP[baseP + i] = n;
        __syncthreads();
        for (int lc = t; lc < nn; lc += 256) csrP[baseP + lptr[lc]] = node0 + lc;
        hist[t] = 1; hist[t + 256] = 1;
        __syncthreads();
        for (int i = t; i < cnt; i += 256) {
            unsigned int p = pairs[base + i];
            int lc = p & (BSPAN - 1);
            int rank = atomicAdd(&hist[lc], 1);
            csrP[baseP + lptr[lc] + rank] = (int)(p >> BSHIFT);
        }
    }
}

// zero row n of both fp8 feature buffers (padding target)
__global__ void zero_rows(unsigned char* T1, unsigned char* T2, int n) {
    int t = threadIdx.x;
    uint4 z = make_uint4(0, 0, 0, 0);
    if (t < 8) ((uint4*)(T1 + (size_t)n * 128))[t] = z;
    else if (t < 16) ((uint4*)(T2 + (size_t)n * 128))[t - 8] = z;
}

// ---------------- W1,W2 -> B-fragment layout (fp16), one launch ----------------
// F2 rows permuted: gemm2's K-dim is the permuted h1 layout, dim(k)=((k&7)<<4)|(k>>3).
__global__ __launch_bounds__(256) void prep_wfrags(const float* __restrict__ W1,
                                                   const float* __restrict__ W2,
                                                   uint4* __restrict__ F1,
                                                   uint4* __restrict__ F2) {
    int g = blockIdx.x * 256 + threadIdx.x;   // 0..4095
    bool second = (g >= 2048);
    const float* W = second ? W2 : W1;
    uint4* F = second ? F2 : F1;
    int t = g & 2047;
    int lane = t & 63, ct = (t >> 6) & 7, ks = t >> 9;
    int col = ct * 16 + (lane & 15);
    int kb = ks * 32 + (lane >> 4) * 8;
    half8 v;
#pragma unroll
    for (int j = 0; j < 8; j++) {
        int k = kb + j;
        int krow = second ? (((k & 7) << 4) | (k >> 3)) : k;
        v[j] = (_Float16)W[krow * 128 + col];
    }
    F[t] = __builtin_bit_cast(uint4, v);
}

// ---------------- MFMA GEMM: T8[r, p] = fp8( dinv[r] * (A[r,:] @ W) ), permuted p ----
template <bool HALF_IN>
__global__ __launch_bounds__(256) void gemm_mfma(const void* __restrict__ Ap,
                                                 const uint4* __restrict__ F,
                                                 const float* __restrict__ dinv,
                                                 unsigned char* __restrict__ T8, int n) {
    int w = threadIdx.x >> 6, lane = threadIdx.x & 63;
    int r0 = blockIdx.x * 128 + w * 32;
    int rA0 = r0 + (lane & 15);
    int rA1 = rA0 + 16;
    int kc = lane >> 4;
    floatx4 acc[2][8] = {};

#pragma unroll
    for (int ks = 0; ks < 4; ks++) {
        half8 a0 = {}, a1 = {};
        if constexpr (HALF_IN) {
            const uint4* A4 = (const uint4*)Ap;
            if (rA0 < n) a0 = __builtin_bit_cast(half8, A4[(size_t)rA0 * 16 + ks * 4 + kc]);
            if (rA1 < n) a1 = __builtin_bit_cast(half8, A4[(size_t)rA1 * 16 + ks * 4 + kc]);
        } else {
            const float* Af = (const float*)Ap;
            if (rA0 < n) {
                const float4* p = (const float4*)&Af[(size_t)rA0 * 128 + ks * 32 + kc * 8];
                float4 u = p[0], v = p[1];
                a0[0] = (_Float16)u.x; a0[1] = (_Float16)u.y; a0[2] = (_Float16)u.z; a0[3] = (_Float16)u.w;
                a0[4] = (_Float16)v.x; a0[5] = (_Float16)v.y; a0[6] = (_Float16)v.z; a0[7] = (_Float16)v.w;
            }
            if (rA1 < n) {
                const float4* p = (const float4*)&Af[(size_t)rA1 * 128 + ks * 32 + kc * 8];
                float4 u = p[0], v = p[1];
                a1[0] = (_Float16)u.x; a1[1] = (_Float16)u.y; a1[2] = (_Float16)u.z; a1[3] = (_Float16)u.w;
                a1[4] = (_Float16)v.x; a1[5] = (_Float16)v.y; a1[6] = (_Float16)v.z; a1[7] = (_Float16)v.w;
            }
        }
        half8 b[8];
#pragma unroll
        for (int ct = 0; ct < 8; ct++)
            b[ct] = __builtin_bit_cast(half8, F[ks * 512 + ct * 64 + lane]);
#pragma unroll
        for (int ct = 0; ct < 8; ct++) {
            acc[0][ct] = __builtin_amdgcn_mfma_f32_16x16x32_f16(a0, b[ct], acc[0][ct], 0, 0, 0);
            acc[1][ct] = __builtin_amdgcn_mfma_f32_16x16x32_f16(a1, b[ct], acc[1][ct], 0, 0, 0);
        }
    }

    int c = lane & 15;
#pragma unroll
    for (int rt = 0; rt < 2; rt++) {
        int rbase = r0 + rt * 16 + (lane >> 4) * 4;
#pragma unroll
        for (int reg = 0; reg < 4; reg++) {
            int r = rbase + reg;
            if (r < n) {
                float di = dinv[r];
                float vv[8];
#pragma unroll
                for (int ct = 0; ct < 8; ct++) vv[ct] = acc[rt][ct][reg] * di;
                int d0 = __builtin_amdgcn_cvt_pk_fp8_f32(vv[0], vv[1], 0, false);
                d0 = __builtin_amdgcn_cvt_pk_fp8_f32(vv[2], vv[3], d0, true);
                int d1 = __builtin_amdgcn_cvt_pk_fp8_f32(vv[4], vv[5], 0, false);
                d1 = __builtin_amdgcn_cvt_pk_fp8_f32(vv[6], vv[7], d1, true);
                *(uint2*)(T8 + (size_t)r * 128 + c * 8) = make_uint2((unsigned)d0, (unsigned)d1);
            }
        }
    }
}

// ---------------- aggregation: wave/node over padded fp8 CSR ----------------
// 16 lanes/edge (uint2 = 8 fp8/lane), 4 edges/iter, branchless (self + zero-row pad).
__global__ __launch_bounds__(256) void aggregate(const unsigned char* __restrict__ T8,
                                                 const int* __restrict__ csrP,
                                                 const int* __restrict__ rowptrP,
                                                 const int* __restrict__ rowEndP,
                                                 const float* __restrict__ dinv,
                                                 const float* __restrict__ bias,
                                                 unsigned int* __restrict__ Out, int n) {
    int node = (int)((blockIdx.x * 256 + threadIdx.x) >> 6);
    int lane = threadIdx.x & 63;
    if (node >= n) return;
    int grp = lane >> 4, m = lane & 15;
    unsigned mo = (unsigned)m << 3;

    floatx2 acc[4] = {};
    int e = rowptrP[node], end = rowEndP[node];
    while (e < end) {
        int take = min(end - e, 64);     // multiple of 4, wave-uniform
        int myidx = csrP[e + lane];
#pragma unroll 4
        for (int j = 0; j < take; j += 4) {
            int src = __shfl(myidx, j + grp);
            uint2 v = *(const uint2*)(T8 + (((unsigned)src << 7) | mo));
            fp8_acc8(acc, v);
        }
        e += take;
    }
    float* af = (float*)acc;
#pragma unroll
    for (int q = 0; q < 8; q++) {
        af[q] += __shfl_xor(af[q], 16);
        af[q] += __shfl_xor(af[q], 32);
    }

    // epilogue: byte pair q = m*8 + 2*grp -> acc slot grp; dim = grp*32 + m (+16)
    floatx2 a = acc[grp];
    int dim = (grp << 5) | m;
    float di = dinv[node];
    float o0 = tanh_fast(a.x * di + bias[dim]);
    float o1 = tanh_fast(a.y * di + bias[dim + 16]);
    Out[(size_t)node * 64 + m * 4 + grp] =
        __builtin_bit_cast(unsigned int, __floats2half2_rn(o0, o1));
}

// same, fused with classifier head: logits[node] = tanh(h)·Wc + bc
__global__ __launch_bounds__(256) void aggregate_logits(const unsigned char* __restrict__ T8,
                                                        const int* __restrict__ csrP,
                                                        const int* __restrict__ rowptrP,
                                                        const int* __restrict__ rowEndP,
                                                        const float* __restrict__ dinv,
                                                        const float* __restrict__ bias,
                                                        const float* __restrict__ Wc,
                                                        const float* __restrict__ bc,
                                                        float* __restrict__ logits, int n) {
    int node = (int)((blockIdx.x * 256 + threadIdx.x) >> 6);
    int lane = threadIdx.x & 63;
    if (node >= n) return;
    int grp = lane >> 4, m = lane & 15;
    unsigned mo = (unsigned)m << 3;

    floatx2 acc[4] = {};
    int e = rowptrP[node], end = rowEndP[node];
    while (e < end) {
        int take = min(end - e, 64);
        int myidx = csrP[e + lane];
#pragma unroll 4
        for (int j = 0; j < take; j += 4) {
            int src = __shfl(myidx, j + grp);
            uint2 v = *(const uint2*)(T8 + (((unsigned)src << 7) | mo));
            fp8_acc8(acc, v);
        }
        e += take;
    }
    float* af = (float*)acc;
#pragma unroll
    for (int q = 0; q < 8; q++) {
        af[q] += __shfl_xor(af[q], 16);
        af[q] += __shfl_xor(af[q], 32);
    }

    floatx2 a = acc[grp];
    int dim = (grp << 5) | m;
    float di = dinv[node];
    float d = tanh_fast(a.x * di + bias[dim]) * Wc[dim]
            + tanh_fast(a.y * di + bias[dim + 16]) * Wc[dim + 16];
#pragma unroll
    for (int off = 1; off < 64; off <<= 1) d += __shfl_xor(d, off);
    if (lane == 0) logits[node] = d + bc[0];
}

// ---------------- softmax over N ----------------
__global__ __launch_bounds__(256) void maxpart(const float* __restrict__ logits, int n,
                                               float* __restrict__ partialMax,
                                               float* __restrict__ denom) {
    if (blockIdx.x == 0 && threadIdx.x == 0) *denom = 0.0f;
    __shared__ float s[256];
    float m = -3.4e38f;
    for (int i = blockIdx.x * 256 + threadIdx.x; i < n; i += 256 * 256)
        m = fmaxf(m, logits[i]);
    s[threadIdx.x] = m;
    __syncthreads();
    for (int d = 128; d; d >>= 1) {
        if (threadIdx.x < d) s[threadIdx.x] = fmaxf(s[threadIdx.x], s[threadIdx.x + d]);
        __syncthreads();
    }
    if (threadIdx.x == 0) partialMax[blockIdx.x] = s[0];
}

__global__ __launch_bounds__(256) void exp_kernel(const float* __restrict__ logits,
                                                  const float* __restrict__ partialMax,
                                                  float* __restrict__ outv,
                                                  float* __restrict__ denom, int n) {
    __shared__ float s[256];
    s[threadIdx.x] = partialMax[threadIdx.x];
    __syncthreads();
    for (int d = 128; d; d >>= 1) {
        if (threadIdx.x < d) s[threadIdx.x] = fmaxf(s[threadIdx.x], s[threadIdx.x + d]);
        __syncthreads();
    }
    float maxv = s[0];
    __syncthreads();
    int i = blockIdx.x * 256 + threadIdx.x;
    float e = 0.0f;
    if (i < n) {
        e = expf(logits[i] - maxv);
        outv[i] = e;
    }
    s[threadIdx.x] = e;
    __syncthreads();
    for (int d = 128; d; d >>= 1) {
        if (threadIdx.x < d) s[threadIdx.x] += s[threadIdx.x + d];
        __syncthreads();
    }
    if (threadIdx.x == 0) atomicAdd(denom, s[0]);
}

__global__ __launch_bounds__(256) void norm_kernel(float* __restrict__ out,
                                                   const float* __restrict__ denom, int n) {
    int i = blockIdx.x * 256 + threadIdx.x;
    if (i < n) out[i] = out[i] / (*denom);
}

extern "C" void kernel_launch(void* const* d_in, const int* in_sizes, int n_in,
                              void* d_out, int out_size, void* d_ws, size_t ws_size,
                              hipStream_t stream) {
    const float* x  = (const float*)d_in[0];
    const int*   ei = (const int*)d_in[1];   // [2,E] int32 (JAX x64 disabled)
    const float* W1 = (const float*)d_in[2];
    const float* b1 = (const float*)d_in[3];
    const float* W2 = (const float*)d_in[4];
    const float* b2 = (const float*)d_in[5];
    const float* Wc = (const float*)d_in[6];
    const float* bc = (const float*)d_in[7];

    int n = in_sizes[0] / 128;
    int E = in_sizes[1] / 2;
    const int* row = ei;
    const int* col = ei + E;
    int NB = (n + BSPAN - 1) >> BSHIFT;

    char* ws = (char*)d_ws;
    size_t off = 0;
    auto alloc = [&](size_t bytes) -> void* {
        void* p = ws + off;
        off += (bytes + 255) & ~(size_t)255;
        return p;
    };
    unsigned char* T1 = (unsigned char*)alloc((size_t)(n + 1) * 128);  // fp8 (+zero row)
    unsigned char* T2 = (unsigned char*)alloc((size_t)(n + 1) * 128);
    unsigned int*  H1 = (unsigned int*)alloc((size_t)n * 128 * 2);     // fp16 h1 (permuted)
    int*    csrP     = (int*)alloc(((size_t)E + (size_t)NB * BPAD + 64) * 4);
    unsigned int* pairs = (unsigned int*)alloc((size_t)E * 4);
    float*  dinv     = (float*)alloc((size_t)n * 4);
    int*    rowptrP  = (int*)alloc((size_t)(n + 1) * 4);
    int*    rowEndP  = (int*)alloc((size_t)n * 4);
    int*    bucketCnt= (int*)alloc(256 * 4);
    int*    bucketPtr= (int*)alloc(257 * 4);
    int*    cursor   = (int*)alloc(256 * 4);
    uint4*  F1       = (uint4*)alloc(2048 * 16);
    uint4*  F2       = (uint4*)alloc(2048 * 16);
    float*  logits   = (float*)alloc((size_t)n * 4);
    float*  pmax     = (float*)alloc(256 * 4);
    float*  denom    = (float*)alloc(4);

    int nbN = (n + 255) / 256;
    int nbW = (n + 3) / 4;
    int nbG = (n + 127) / 128;

    hipMemsetAsync(bucketCnt, 0, 256 * 4, stream);

    hist_buckets<<<512, 256, 0, stream>>>(col, E, bucketCnt);
    scan_buckets<<<1, 256, 0, stream>>>(bucketCnt, bucketPtr, cursor, NB, E);
    partition_edges<<<(E + PCHUNK - 1) / PCHUNK, 256, 0, stream>>>(row, col, E, cursor, pairs);
    prep_wfrags<<<16, 256, 0, stream>>>(W1, W2, F1, F2);
    build_bucket_csr<<<NB, 256, 0, stream>>>(pairs, bucketPtr, rowptrP, rowEndP, dinv,
                                             csrP, n, NB, E);
    zero_rows<<<1, 64, 0, stream>>>(T1, T2, n);

    gemm_mfma<false><<<nbG, 256, 0, stream>>>(x, F1, dinv, T1, n);
    aggregate<<<nbW, 256, 0, stream>>>(T1, csrP, rowptrP, rowEndP, dinv, b1, H1, n);
    gemm_mfma<true><<<nbG, 256, 0, stream>>>(H1, F2, dinv, T2, n);
    aggregate_logits<<<nbW, 256, 0, stream>>>(T2, csrP, rowptrP, rowEndP, dinv, b2, Wc, bc,
                                              logits, n);

    maxpart<<<256, 256, 0, stream>>>(logits, n, pmax, denom);
    exp_kernel<<<nbN, 256, 0, stream>>>(logits, pmax, (float*)d_out, denom, n);
    norm_kernel<<<nbN, 256, 0, stream>>>((float*)d_out, denom, n);
}

// Round 13
// 204.940 us; speedup vs baseline: 1.5303x; 1.0662x over previous
//
#include <hip/hip_runtime.h>
#include <hip/hip_fp16.h>

// GCN: 2x (linear -> deg-normalized scatter-add -> bias -> tanh) -> linear(1) -> softmax(N)
// R12: latency attack on the gather loop (VGPR=16 showed zero load pipelining):
// degrees padded to 8; two explicit loads/step into two independent accumulator
// sets (acc/acc2) + unroll 2 => 2-4 gathers in flight per lane. Rest unchanged:
// fp8 features, padded branchless CSR (self-loop as edge, dummies -> zero row),
// MFMA f16 GEMMs with fused fp8-permuted epilogue, bucket-sort CSR build.

#define BSHIFT 9
#define BSPAN  512
#define PCHUNK 4096
#define LCAP   12288
#define BPAD   4096   // max padding per bucket: 512 nodes * 8

typedef _Float16 half8 __attribute__((ext_vector_type(8)));
typedef float floatx4 __attribute__((ext_vector_type(4)));
typedef float floatx2 __attribute__((ext_vector_type(2)));

// exact-saturating fast tanh: 1 - 2/(e^2x + 1)
__device__ inline float tanh_fast(float x) {
    float e = __expf(2.0f * x);
    return 1.0f - 2.0f * __builtin_amdgcn_rcpf(e + 1.0f);
}

// accumulate 8 fp8 (one uint2) into 4 packed-f32 accumulators
__device__ inline void fp8_acc8(floatx2* acc, uint2 v) {
    acc[0] += __builtin_amdgcn_cvt_pk_f32_fp8((int)v.x, false);
    acc[1] += __builtin_amdgcn_cvt_pk_f32_fp8((int)v.x, true);
    acc[2] += __builtin_amdgcn_cvt_pk_f32_fp8((int)v.y, false);
    acc[3] += __builtin_amdgcn_cvt_pk_f32_fp8((int)v.y, true);
}

// ---------------- CSR build (2-level bucket counting sort) ----------------
__global__ __launch_bounds__(256) void hist_buckets(const int* __restrict__ col, int E,
                                                    int* __restrict__ bucketCnt) {
    __shared__ int h[256];
    h[threadIdx.x] = 0;
    __syncthreads();
    for (int e = blockIdx.x * 256 + threadIdx.x; e < E; e += gridDim.x * 256)
        atomicAdd(&h[col[e] >> BSHIFT], 1);
    __syncthreads();
    int v = h[threadIdx.x];
    if (v) atomicAdd(&bucketCnt[threadIdx.x], v);
}

__global__ void scan_buckets(const int* __restrict__ cnt, int* __restrict__ bucketPtr,
                             int* __restrict__ cursor, int NB, int E) {
    __shared__ int s[256];
    int t = threadIdx.x;
    int v = (t < NB) ? cnt[t] : 0;
    s[t] = v;
    __syncthreads();
    for (int d = 1; d < 256; d <<= 1) {
        int x = (t >= d) ? s[t - d] : 0;
        __syncthreads();
        s[t] += x;
        __syncthreads();
    }
    if (t < NB) {
        int p = s[t] - v;
        bucketPtr[t] = p;
        cursor[t] = p;
    }
    if (t == 0) bucketPtr[NB] = E;
}

// pairs packed: (src << BSHIFT) | (dst & (BSPAN-1))   [src < 2^23]
__global__ __launch_bounds__(256) void partition_edges(const int* __restrict__ row,
                                                       const int* __restrict__ col, int E,
                                                       int* __restrict__ cursor,
                                                       unsigned int* __restrict__ pairs) {
    __shared__ int hist[256], sscan[256], gdelta[256], hcur[256];
    __shared__ uint2 stage[PCHUNK];
    int t = threadIdx.x;
    int base = blockIdx.x * PCHUNK;
    int cnt = min(PCHUNK, E - base);
    hist[t] = 0;
    __syncthreads();
    uint2 v[16];
    int b_[16];
#pragma unroll
    for (int k = 0; k < 16; k++) {
        int idx = t + k * 256;
        if (idx < cnt) {
            int c = col[base + idx], r = row[base + idx];
            v[k] = make_uint2((unsigned)c, (unsigned)r);
            b_[k] = c >> BSHIFT;
            atomicAdd(&hist[b_[k]], 1);
        } else b_[k] = -1;
    }
    __syncthreads();
    int hv = hist[t];
    sscan[t] = hv;
    __syncthreads();
    for (int d = 1; d < 256; d <<= 1) {
        int x = (t >= d) ? sscan[t - d] : 0;
        __syncthreads();
        sscan[t] += x;
        __syncthreads();
    }
    int excl = sscan[t] - hv;
    if (hv > 0) {
        int g = atomicAdd(&cursor[t], hv);
        gdelta[t] = g - excl;
    }
    hcur[t] = excl;
    __syncthreads();
#pragma unroll
    for (int k = 0; k < 16; k++) {
        if (b_[k] >= 0) {
            int slot = atomicAdd(&hcur[b_[k]], 1);
            stage[slot] = v[k];
        }
    }
    __syncthreads();
    for (int i = t; i < cnt; i += 256) {
        uint2 p = stage[i];
        pairs[gdelta[p.x >> BSHIFT] + i] = (p.y << BSHIFT) | (p.x & (BSPAN - 1));
    }
}

// ---- per bucket: padded CSR (multiple of 8). Self-loop at slot 0; padding ->
// zero row (index n). Emits rowptrP (start) AND rowEndP (start + paddedDeg). ----
__global__ __launch_bounds__(256) void build_bucket_csr(const unsigned int* __restrict__ pairs,
                                                        const int* __restrict__ bucketPtr,
                                                        int* __restrict__ rowptrP,
                                                        int* __restrict__ rowEndP,
                                                        float* __restrict__ dinv,
                                                        int* __restrict__ csrP,
                                                        int n, int NB, int E) {
    __shared__ int hist[BSPAN];
    __shared__ int lptr[BSPAN];
    __shared__ int s[256];
    __shared__ int srcStage[LCAP];
    __shared__ int totp;
    int b = blockIdx.x, t = threadIdx.x;
    int base = bucketPtr[b], cnt = bucketPtr[b + 1] - base;
    int baseP = base + b * BPAD;
    int node0 = b << BSHIFT;
    int nn = min(BSPAN, n - node0);
    hist[t] = 0; hist[t + 256] = 0;
    __syncthreads();
    for (int i = t; i < cnt; i += 256)
        atomicAdd(&hist[pairs[base + i] & (BSPAN - 1)], 1);
    __syncthreads();
    // padded degrees (deg + 1 self, rounded up to 8); phantom nodes get 0
    int d0 = (2 * t < nn)     ? ((hist[2 * t] + 8) & ~7)     : 0;
    int d1 = (2 * t + 1 < nn) ? ((hist[2 * t + 1] + 8) & ~7) : 0;
    int sum = d0 + d1;
    s[t] = sum;
    __syncthreads();
    for (int d = 1; d < 256; d <<= 1) {
        int x = (t >= d) ? s[t - d] : 0;
        __syncthreads();
        s[t] += x;
        __syncthreads();
    }
    int excl = s[t] - sum;
    lptr[2 * t] = excl;
    lptr[2 * t + 1] = excl + d0;
    if (t == 255) totp = s[255];
    __syncthreads();
    int cntp = totp;
    for (int lc = t; lc < nn; lc += 256) {
        int st = baseP + lptr[lc];
        int dP = (hist[lc] + 8) & ~7;
        rowptrP[node0 + lc] = st;
        rowEndP[node0 + lc] = st + dP;
        dinv[node0 + lc] = rsqrtf((float)(hist[lc] + 1));
    }
    __syncthreads();
    bool inLds = (cntp <= LCAP);
    if (inLds) {
        for (int i = t; i < cntp; i += 256) srcStage[i] = n;          // zero-row pad
        __syncthreads();
        for (int lc = t; lc < nn; lc += 256) srcStage[lptr[lc]] = node0 + lc;  // self
        hist[t] = 1; hist[t + 256] = 1;                               // cursors (after self)
        __syncthreads();
        for (int i = t; i < cnt; i += 256) {
            unsigned int p = pairs[base + i];
            int lc = p & (BSPAN - 1);
            int rank = atomicAdd(&hist[lc], 1);
            srcStage[lptr[lc] + rank] = (int)(p >> BSHIFT);
        }
        __syncthreads();
        for (int i = t; i < cntp; i += 256) csrP[baseP + i] = srcStage[i];
    } else {   // rare fallback: direct global
        for (int i = t; i < cntp; i += 256) csrP[baseP + i] = n;
        __syncthreads();
        for (int lc = t; lc < nn; lc += 256) csrP[baseP + lptr[lc]] = node0 + lc;
        hist[t] = 1; hist[t + 256] = 1;
        __syncthreads();
        for (int i = t; i < cnt; i += 256) {
            unsigned int p = pairs[base + i];
            int lc = p & (BSPAN - 1);
            int rank = atomicAdd(&hist[lc], 1);
            csrP[baseP + lptr[lc] + rank] = (int)(p >> BSHIFT);
        }
    }
}

// zero row n of both fp8 feature buffers (padding target)
__global__ void zero_rows(unsigned char* T1, unsigned char* T2, int n) {
    int t = threadIdx.x;
    uint4 z = make_uint4(0, 0, 0, 0);
    if (t < 8) ((uint4*)(T1 + (size_t)n * 128))[t] = z;
    else if (t < 16) ((uint4*)(T2 + (size_t)n * 128))[t - 8] = z;
}

// ---------------- W1,W2 -> B-fragment layout (fp16), one launch ----------------
// F2 rows permuted: gemm2's K-dim is the permuted h1 layout, dim(k)=((k&7)<<4)|(k>>3).
__global__ __launch_bounds__(256) void prep_wfrags(const float* __restrict__ W1,
                                                   const float* __restrict__ W2,
                                                   uint4* __restrict__ F1,
                                                   uint4* __restrict__ F2) {
    int g = blockIdx.x * 256 + threadIdx.x;   // 0..4095
    bool second = (g >= 2048);
    const float* W = second ? W2 : W1;
    uint4* F = second ? F2 : F1;
    int t = g & 2047;
    int lane = t & 63, ct = (t >> 6) & 7, ks = t >> 9;
    int col = ct * 16 + (lane & 15);
    int kb = ks * 32 + (lane >> 4) * 8;
    half8 v;
#pragma unroll
    for (int j = 0; j < 8; j++) {
        int k = kb + j;
        int krow = second ? (((k & 7) << 4) | (k >> 3)) : k;
        v[j] = (_Float16)W[krow * 128 + col];
    }
    F[t] = __builtin_bit_cast(uint4, v);
}

// ---------------- MFMA GEMM: T8[r, p] = fp8( dinv[r] * (A[r,:] @ W) ), permuted p ----
template <bool HALF_IN>
__global__ __launch_bounds__(256) void gemm_mfma(const void* __restrict__ Ap,
                                                 const uint4* __restrict__ F,
                                                 const float* __restrict__ dinv,
                                                 unsigned char* __restrict__ T8, int n) {
    int w = threadIdx.x >> 6, lane = threadIdx.x & 63;
    int r0 = blockIdx.x * 128 + w * 32;
    int rA0 = r0 + (lane & 15);
    int rA1 = rA0 + 16;
    int kc = lane >> 4;
    floatx4 acc[2][8] = {};

#pragma unroll
    for (int ks = 0; ks < 4; ks++) {
        half8 a0 = {}, a1 = {};
        if constexpr (HALF_IN) {
            const uint4* A4 = (const uint4*)Ap;
            if (rA0 < n) a0 = __builtin_bit_cast(half8, A4[(size_t)rA0 * 16 + ks * 4 + kc]);
            if (rA1 < n) a1 = __builtin_bit_cast(half8, A4[(size_t)rA1 * 16 + ks * 4 + kc]);
        } else {
            const float* Af = (const float*)Ap;
            if (rA0 < n) {
                const float4* p = (const float4*)&Af[(size_t)rA0 * 128 + ks * 32 + kc * 8];
                float4 u = p[0], v = p[1];
                a0[0] = (_Float16)u.x; a0[1] = (_Float16)u.y; a0[2] = (_Float16)u.z; a0[3] = (_Float16)u.w;
                a0[4] = (_Float16)v.x; a0[5] = (_Float16)v.y; a0[6] = (_Float16)v.z; a0[7] = (_Float16)v.w;
            }
            if (rA1 < n) {
                const float4* p = (const float4*)&Af[(size_t)rA1 * 128 + ks * 32 + kc * 8];
                float4 u = p[0], v = p[1];
                a1[0] = (_Float16)u.x; a1[1] = (_Float16)u.y; a1[2] = (_Float16)u.z; a1[3] = (_Float16)u.w;
                a1[4] = (_Float16)v.x; a1[5] = (_Float16)v.y; a1[6] = (_Float16)v.z; a1[7] = (_Float16)v.w;
            }
        }
        half8 b[8];
#pragma unroll
        for (int ct = 0; ct < 8; ct++)
            b[ct] = __builtin_bit_cast(half8, F[ks * 512 + ct * 64 + lane]);
#pragma unroll
        for (int ct = 0; ct < 8; ct++) {
            acc[0][ct] = __builtin_amdgcn_mfma_f32_16x16x32_f16(a0, b[ct], acc[0][ct], 0, 0, 0);
            acc[1][ct] = __builtin_amdgcn_mfma_f32_16x16x32_f16(a1, b[ct], acc[1][ct], 0, 0, 0);
        }
    }

    int c = lane & 15;
#pragma unroll
    for (int rt = 0; rt < 2; rt++) {
        int rbase = r0 + rt * 16 + (lane >> 4) * 4;
#pragma unroll
        for (int reg = 0; reg < 4; reg++) {
            int r = rbase + reg;
            if (r < n) {
                float di = dinv[r];
                float vv[8];
#pragma unroll
                for (int ct = 0; ct < 8; ct++) vv[ct] = acc[rt][ct][reg] * di;
                int d0 = __builtin_amdgcn_cvt_pk_fp8_f32(vv[0], vv[1], 0, false);
                d0 = __builtin_amdgcn_cvt_pk_fp8_f32(vv[2], vv[3], d0, true);
                int d1 = __builtin_amdgcn_cvt_pk_fp8_f32(vv[4], vv[5], 0, false);
                d1 = __builtin_amdgcn_cvt_pk_fp8_f32(vv[6], vv[7], d1, true);
                *(uint2*)(T8 + (size_t)r * 128 + c * 8) = make_uint2((unsigned)d0, (unsigned)d1);
            }
        }
    }
}

// ---------------- aggregation: wave/node over padded fp8 CSR ----------------
// 16 lanes/edge, 8 edges/step as two independent load+acc chains (MLP), unroll 2.
__global__ __launch_bounds__(256) void aggregate(const unsigned char* __restrict__ T8,
                                                 const int* __restrict__ csrP,
                                                 const int* __restrict__ rowptrP,
                                                 const int* __restrict__ rowEndP,
                                                 const float* __restrict__ dinv,
                                                 const float* __restrict__ bias,
                                                 unsigned int* __restrict__ Out, int n) {
    int node = (int)((blockIdx.x * 256 + threadIdx.x) >> 6);
    int lane = threadIdx.x & 63;
    if (node >= n) return;
    int grp = lane >> 4, m = lane & 15;
    unsigned mo = (unsigned)m << 3;

    floatx2 acc[4] = {}, acc2[4] = {};
    int e = rowptrP[node], end = rowEndP[node];   // end-e multiple of 8
    while (e < end) {
        int take = min(end - e, 64);     // multiple of 8, wave-uniform
        int myidx = csrP[e + lane];
#pragma unroll 2
        for (int j = 0; j < take; j += 8) {
            int sA = __shfl(myidx, j + grp);
            int sB = __shfl(myidx, j + 4 + grp);
            uint2 vA = *(const uint2*)(T8 + (((unsigned)sA << 7) | mo));
            uint2 vB = *(const uint2*)(T8 + (((unsigned)sB << 7) | mo));
            fp8_acc8(acc, vA);
            fp8_acc8(acc2, vB);
        }
        e += take;
    }
#pragma unroll
    for (int q = 0; q < 4; q++) acc[q] += acc2[q];
    float* af = (float*)acc;
#pragma unroll
    for (int q = 0; q < 8; q++) {
        af[q] += __shfl_xor(af[q], 16);
        af[q] += __shfl_xor(af[q], 32);
    }

    // epilogue: byte pair q = m*8 + 2*grp -> acc slot grp; dim = grp*32 + m (+16)
    floatx2 a = acc[grp];
    int dim = (grp << 5) | m;
    float di = dinv[node];
    float o0 = tanh_fast(a.x * di + bias[dim]);
    float o1 = tanh_fast(a.y * di + bias[dim + 16]);
    Out[(size_t)node * 64 + m * 4 + grp] =
        __builtin_bit_cast(unsigned int, __floats2half2_rn(o0, o1));
}

// same, fused with classifier head: logits[node] = tanh(h)·Wc + bc
__global__ __launch_bounds__(256) void aggregate_logits(const unsigned char* __restrict__ T8,
                                                        const int* __restrict__ csrP,
                                                        const int* __restrict__ rowptrP,
                                                        const int* __restrict__ rowEndP,
                                                        const float* __restrict__ dinv,
                                                        const float* __restrict__ bias,
                                                        const float* __restrict__ Wc,
                                                        const float* __restrict__ bc,
                                                        float* __restrict__ logits, int n) {
    int node = (int)((blockIdx.x * 256 + threadIdx.x) >> 6);
    int lane = threadIdx.x & 63;
    if (node >= n) return;
    int grp = lane >> 4, m = lane & 15;
    unsigned mo = (unsigned)m << 3;

    floatx2 acc[4] = {}, acc2[4] = {};
    int e = rowptrP[node], end = rowEndP[node];
    while (e < end) {
        int take = min(end - e, 64);
        int myidx = csrP[e + lane];
#pragma unroll 2
        for (int j = 0; j < take; j += 8) {
            int sA = __shfl(myidx, j + grp);
            int sB = __shfl(myidx, j + 4 + grp);
            uint2 vA = *(const uint2*)(T8 + (((unsigned)sA << 7) | mo));
            uint2 vB = *(const uint2*)(T8 + (((unsigned)sB << 7) | mo));
            fp8_acc8(acc, vA);
            fp8_acc8(acc2, vB);
        }
        e += take;
    }
#pragma unroll
    for (int q = 0; q < 4; q++) acc[q] += acc2[q];
    float* af = (float*)acc;
#pragma unroll
    for (int q = 0; q < 8; q++) {
        af[q] += __shfl_xor(af[q], 16);
        af[q] += __shfl_xor(af[q], 32);
    }

    floatx2 a = acc[grp];
    int dim = (grp << 5) | m;
    float di = dinv[node];
    float d = tanh_fast(a.x * di + bias[dim]) * Wc[dim]
            + tanh_fast(a.y * di + bias[dim + 16]) * Wc[dim + 16];
#pragma unroll
    for (int off = 1; off < 64; off <<= 1) d += __shfl_xor(d, off);
    if (lane == 0) logits[node] = d + bc[0];
}

// ---------------- softmax over N ----------------
__global__ __launch_bounds__(256) void maxpart(const float* __restrict__ logits, int n,
                                               float* __restrict__ partialMax,
                                               float* __restrict__ denom) {
    if (blockIdx.x == 0 && threadIdx.x == 0) *denom = 0.0f;
    __shared__ float s[256];
    float m = -3.4e38f;
    for (int i = blockIdx.x * 256 + threadIdx.x; i < n; i += 256 * 256)
        m = fmaxf(m, logits[i]);
    s[threadIdx.x] = m;
    __syncthreads();
    for (int d = 128; d; d >>= 1) {
        if (threadIdx.x < d) s[threadIdx.x] = fmaxf(s[threadIdx.x], s[threadIdx.x + d]);
        __syncthreads();
    }
    if (threadIdx.x == 0) partialMax[blockIdx.x] = s[0];
}

__global__ __launch_bounds__(256) void exp_kernel(const float* __restrict__ logits,
                                                  const float* __restrict__ partialMax,
                                                  float* __restrict__ outv,
                                                  float* __restrict__ denom, int n) {
    __shared__ float s[256];
    s[threadIdx.x] = partialMax[threadIdx.x];
    __syncthreads();
    for (int d = 128; d; d >>= 1) {
        if (threadIdx.x < d) s[threadIdx.x] = fmaxf(s[threadIdx.x], s[threadIdx.x + d]);
        __syncthreads();
    }
    float maxv = s[0];
    __syncthreads();
    int i = blockIdx.x * 256 + threadIdx.x;
    float e = 0.0f;
    if (i < n) {
        e = expf(logits[i] - maxv);
        outv[i] = e;
    }
    s[threadIdx.x] = e;
    __syncthreads();
    for (int d = 128; d; d >>= 1) {
        if (threadIdx.x < d) s[threadIdx.x] += s[threadIdx.x + d];
        __syncthreads();
    }
    if (threadIdx.x == 0) atomicAdd(denom, s[0]);
}

__global__ __launch_bounds__(256) void norm_kernel(float* __restrict__ out,
                                                   const float* __restrict__ denom, int n) {
    int i = blockIdx.x * 256 + threadIdx.x;
    if (i < n) out[i] = out[i] / (*denom);
}

extern "C" void kernel_launch(void* const* d_in, const int* in_sizes, int n_in,
                              void* d_out, int out_size, void* d_ws, size_t ws_size,
                              hipStream_t stream) {
    const float* x  = (const float*)d_in[0];
    const int*   ei = (const int*)d_in[1];   // [2,E] int32 (JAX x64 disabled)
    const float* W1 = (const float*)d_in[2];
    const float* b1 = (const float*)d_in[3];
    const float* W2 = (const float*)d_in[4];
    const float* b2 = (const float*)d_in[5];
    const float* Wc = (const float*)d_in[6];
    const float* bc = (const float*)d_in[7];

    int n = in_sizes[0] / 128;
    int E = in_sizes[1] / 2;
    const int* row = ei;
    const int* col = ei + E;
    int NB = (n + BSPAN - 1) >> BSHIFT;

    char* ws = (char*)d_ws;
    size_t off = 0;
    auto alloc = [&](size_t bytes) -> void* {
        void* p = ws + off;
        off += (bytes + 255) & ~(size_t)255;
        return p;
    };
    unsigned char* T1 = (unsigned char*)alloc((size_t)(n + 1) * 128);  // fp8 (+zero row)
    unsigned char* T2 = (unsigned char*)alloc((size_t)(n + 1) * 128);
    unsigned int*  H1 = (unsigned int*)alloc((size_t)n * 128 * 2);     // fp16 h1 (permuted)
    int*    csrP     = (int*)alloc(((size_t)E + (size_t)NB * BPAD + 64) * 4);
    unsigned int* pairs = (unsigned int*)alloc((size_t)E * 4);
    float*  dinv     = (float*)alloc((size_t)n * 4);
    int*    rowptrP  = (int*)alloc((size_t)(n + 1) * 4);
    int*    rowEndP  = (int*)alloc((size_t)n * 4);
    int*    bucketCnt= (int*)alloc(256 * 4);
    int*    bucketPtr= (int*)alloc(257 * 4);
    int*    cursor   = (int*)alloc(256 * 4);
    uint4*  F1       = (uint4*)alloc(2048 * 16);
    uint4*  F2       = (uint4*)alloc(2048 * 16);
    float*  logits   = (float*)alloc((size_t)n * 4);
    float*  pmax     = (float*)alloc(256 * 4);
    float*  denom    = (float*)alloc(4);

    int nbN = (n + 255) / 256;
    int nbW = (n + 3) / 4;
    int nbG = (n + 127) / 128;

    hipMemsetAsync(bucketCnt, 0, 256 * 4, stream);

    hist_buckets<<<512, 256, 0, stream>>>(col, E, bucketCnt);
    scan_buckets<<<1, 256, 0, stream>>>(bucketCnt, bucketPtr, cursor, NB, E);
    partition_edges<<<(E + PCHUNK - 1) / PCHUNK, 256, 0, stream>>>(row, col, E, cursor, pairs);
    prep_wfrags<<<16, 256, 0, stream>>>(W1, W2, F1, F2);
    build_bucket_csr<<<NB, 256, 0, stream>>>(pairs, bucketPtr, rowptrP, rowEndP, dinv,
                                             csrP, n, NB, E);
    zero_rows<<<1, 64, 0, stream>>>(T1, T2, n);

    gemm_mfma<false><<<nbG, 256, 0, stream>>>(x, F1, dinv, T1, n);
    aggregate<<<nbW, 256, 0, stream>>>(T1, csrP, rowptrP, rowEndP, dinv, b1, H1, n);
    gemm_mfma<true><<<nbG, 256, 0, stream>>>(H1, F2, dinv, T2, n);
    aggregate_logits<<<nbW, 256, 0, stream>>>(T2, csrP, rowptrP, rowEndP, dinv, b2, Wc, bc,
                                              logits, n);

    maxpart<<<256, 256, 0, stream>>>(logits, n, pmax, denom);
    exp_kernel<<<nbN, 256, 0, stream>>>(logits, pmax, (float*)d_out, denom, n);
    norm_kernel<<<nbN, 256, 0, stream>>>((float*)d_out, denom, n);
}

// Round 14
// 200.671 us; speedup vs baseline: 1.5629x; 1.0213x over previous
//
#include <hip/hip_runtime.h>
#include <hip/hip_fp16.h>

// GCN: 2x (linear -> deg-normalized scatter-add -> bias -> tanh) -> linear(1) -> softmax(N)
// R13: kill the shuffle in the gather loop — each 16-lane group loads its edge
// index DIRECTLY (csrP[e+j+grp]: 8 consecutive dwords/wave/step, L1-broadcast to
// the group) instead of 64-wide preload + 2 ds_bpermute per step. Index loads are
// data-independent -> pipeline ahead of gathers. zero_rows folded into prep_wfrags.
// Rest as R12: fp8 features, padded branchless CSR, dual acc chains, MFMA GEMMs.

#define BSHIFT 9
#define BSPAN  512
#define PCHUNK 4096
#define LCAP   12288
#define BPAD   4096   // max padding per bucket: 512 nodes * 8

typedef _Float16 half8 __attribute__((ext_vector_type(8)));
typedef float floatx4 __attribute__((ext_vector_type(4)));
typedef float floatx2 __attribute__((ext_vector_type(2)));

// exact-saturating fast tanh: 1 - 2/(e^2x + 1)
__device__ inline float tanh_fast(float x) {
    float e = __expf(2.0f * x);
    return 1.0f - 2.0f * __builtin_amdgcn_rcpf(e + 1.0f);
}

// accumulate 8 fp8 (one uint2) into 4 packed-f32 accumulators
__device__ inline void fp8_acc8(floatx2* acc, uint2 v) {
    acc[0] += __builtin_amdgcn_cvt_pk_f32_fp8((int)v.x, false);
    acc[1] += __builtin_amdgcn_cvt_pk_f32_fp8((int)v.x, true);
    acc[2] += __builtin_amdgcn_cvt_pk_f32_fp8((int)v.y, false);
    acc[3] += __builtin_amdgcn_cvt_pk_f32_fp8((int)v.y, true);
}

// ---------------- CSR build (2-level bucket counting sort) ----------------
__global__ __launch_bounds__(256) void hist_buckets(const int* __restrict__ col, int E,
                                                    int* __restrict__ bucketCnt) {
    __shared__ int h[256];
    h[threadIdx.x] = 0;
    __syncthreads();
    for (int e = blockIdx.x * 256 + threadIdx.x; e < E; e += gridDim.x * 256)
        atomicAdd(&h[col[e] >> BSHIFT], 1);
    __syncthreads();
    int v = h[threadIdx.x];
    if (v) atomicAdd(&bucketCnt[threadIdx.x], v);
}

__global__ void scan_buckets(const int* __restrict__ cnt, int* __restrict__ bucketPtr,
                             int* __restrict__ cursor, int NB, int E) {
    __shared__ int s[256];
    int t = threadIdx.x;
    int v = (t < NB) ? cnt[t] : 0;
    s[t] = v;
    __syncthreads();
    for (int d = 1; d < 256; d <<= 1) {
        int x = (t >= d) ? s[t - d] : 0;
        __syncthreads();
        s[t] += x;
        __syncthreads();
    }
    if (t < NB) {
        int p = s[t] - v;
        bucketPtr[t] = p;
        cursor[t] = p;
    }
    if (t == 0) bucketPtr[NB] = E;
}

// pairs packed: (src << BSHIFT) | (dst & (BSPAN-1))   [src < 2^23]
__global__ __launch_bounds__(256) void partition_edges(const int* __restrict__ row,
                                                       const int* __restrict__ col, int E,
                                                       int* __restrict__ cursor,
                                                       unsigned int* __restrict__ pairs) {
    __shared__ int hist[256], sscan[256], gdelta[256], hcur[256];
    __shared__ uint2 stage[PCHUNK];
    int t = threadIdx.x;
    int base = blockIdx.x * PCHUNK;
    int cnt = min(PCHUNK, E - base);
    hist[t] = 0;
    __syncthreads();
    uint2 v[16];
    int b_[16];
#pragma unroll
    for (int k = 0; k < 16; k++) {
        int idx = t + k * 256;
        if (idx < cnt) {
            int c = col[base + idx], r = row[base + idx];
            v[k] = make_uint2((unsigned)c, (unsigned)r);
            b_[k] = c >> BSHIFT;
            atomicAdd(&hist[b_[k]], 1);
        } else b_[k] = -1;
    }
    __syncthreads();
    int hv = hist[t];
    sscan[t] = hv;
    __syncthreads();
    for (int d = 1; d < 256; d <<= 1) {
        int x = (t >= d) ? sscan[t - d] : 0;
        __syncthreads();
        sscan[t] += x;
        __syncthreads();
    }
    int excl = sscan[t] - hv;
    if (hv > 0) {
        int g = atomicAdd(&cursor[t], hv);
        gdelta[t] = g - excl;
    }
    hcur[t] = excl;
    __syncthreads();
#pragma unroll
    for (int k = 0; k < 16; k++) {
        if (b_[k] >= 0) {
            int slot = atomicAdd(&hcur[b_[k]], 1);
            stage[slot] = v[k];
        }
    }
    __syncthreads();
    for (int i = t; i < cnt; i += 256) {
        uint2 p = stage[i];
        pairs[gdelta[p.x >> BSHIFT] + i] = (p.y << BSHIFT) | (p.x & (BSPAN - 1));
    }
}

// ---- per bucket: padded CSR (multiple of 8). Self-loop at slot 0; padding ->
// zero row (index n). Emits rowptrP (start) AND rowEndP (start + paddedDeg). ----
__global__ __launch_bounds__(256) void build_bucket_csr(const unsigned int* __restrict__ pairs,
                                                        const int* __restrict__ bucketPtr,
                                                        int* __restrict__ rowptrP,
                                                        int* __restrict__ rowEndP,
                                                        float* __restrict__ dinv,
                                                        int* __restrict__ csrP,
                                                        int n, int NB, int E) {
    __shared__ int hist[BSPAN];
    __shared__ int lptr[BSPAN];
    __shared__ int s[256];
    __shared__ int srcStage[LCAP];
    __shared__ int totp;
    int b = blockIdx.x, t = threadIdx.x;
    int base = bucketPtr[b], cnt = bucketPtr[b + 1] - base;
    int baseP = base + b * BPAD;
    int node0 = b << BSHIFT;
    int nn = min(BSPAN, n - node0);
    hist[t] = 0; hist[t + 256] = 0;
    __syncthreads();
    for (int i = t; i < cnt; i += 256)
        atomicAdd(&hist[pairs[base + i] & (BSPAN - 1)], 1);
    __syncthreads();
    // padded degrees (deg + 1 self, rounded up to 8); phantom nodes get 0
    int d0 = (2 * t < nn)     ? ((hist[2 * t] + 8) & ~7)     : 0;
    int d1 = (2 * t + 1 < nn) ? ((hist[2 * t + 1] + 8) & ~7) : 0;
    int sum = d0 + d1;
    s[t] = sum;
    __syncthreads();
    for (int d = 1; d < 256; d <<= 1) {
        int x = (t >= d) ? s[t - d] : 0;
        __syncthreads();
        s[t] += x;
        __syncthreads();
    }
    int excl = s[t] - sum;
    lptr[2 * t] = excl;
    lptr[2 * t + 1] = excl + d0;
    if (t == 255) totp = s[255];
    __syncthreads();
    int cntp = totp;
    for (int lc = t; lc < nn; lc += 256) {
        int st = baseP + lptr[lc];
        int dP = (hist[lc] + 8) & ~7;
        rowptrP[node0 + lc] = st;
        rowEndP[node0 + lc] = st + dP;
        dinv[node0 + lc] = rsqrtf((float)(hist[lc] + 1));
    }
    __syncthreads();
    bool inLds = (cntp <= LCAP);
    if (inLds) {
        for (int i = t; i < cntp; i += 256) srcStage[i] = n;          // zero-row pad
        __syncthreads();
        for (int lc = t; lc < nn; lc += 256) srcStage[lptr[lc]] = node0 + lc;  // self
        hist[t] = 1; hist[t + 256] = 1;                               // cursors (after self)
        __syncthreads();
        for (int i = t; i < cnt; i += 256) {
            unsigned int p = pairs[base + i];
            int lc = p & (BSPAN - 1);
            int rank = atomicAdd(&hist[lc], 1);
            srcStage[lptr[lc] + rank] = (int)(p >> BSHIFT);
        }
        __syncthreads();
        for (int i = t; i < cntp; i += 256) csrP[baseP + i] = srcStage[i];
    } else {   // rare fallback: direct global
        for (int i = t; i < cntp; i += 256) csrP[baseP + i] = n;
        __syncthreads();
        for (int lc = t; lc < nn; lc += 256) csrP[baseP + lptr[lc]] = node0 + lc;
        hist[t] = 1; hist[t + 256] = 1;
        __syncthreads();
        for (int i = t; i < cnt; i += 256) {
            unsigned int p = pairs[base + i];
            int lc = p & (BSPAN - 1);
            int rank = atomicAdd(&hist[lc], 1);
            csrP[baseP + lptr[lc] + rank] = (int)(p >> BSHIFT);
        }
    }
}

// ---------------- W1,W2 -> B-fragment layout (fp16) + zero pad rows, one launch ----
// F2 rows permuted: gemm2's K-dim is the permuted h1 layout, dim(k)=((k&7)<<4)|(k>>3).
// Blocks 16.. zero row n of T1/T2 (gather padding target).
__global__ __launch_bounds__(256) void prep_wfrags(const float* __restrict__ W1,
                                                   const float* __restrict__ W2,
                                                   uint4* __restrict__ F1,
                                                   uint4* __restrict__ F2,
                                                   unsigned char* __restrict__ T1,
                                                   unsigned char* __restrict__ T2, int n) {
    int g = blockIdx.x * 256 + threadIdx.x;   // 0..4351
    if (g >= 4096) {
        int t = g - 4096;
        uint4 z = make_uint4(0, 0, 0, 0);
        if (t < 8) ((uint4*)(T1 + (size_t)n * 128))[t] = z;
        else if (t < 16) ((uint4*)(T2 + (size_t)n * 128))[t - 8] = z;
        return;
    }
    bool second = (g >= 2048);
    const float* W = second ? W2 : W1;
    uint4* F = second ? F2 : F1;
    int t = g & 2047;
    int lane = t & 63, ct = (t >> 6) & 7, ks = t >> 9;
    int col = ct * 16 + (lane & 15);
    int kb = ks * 32 + (lane >> 4) * 8;
    half8 v;
#pragma unroll
    for (int j = 0; j < 8; j++) {
        int k = kb + j;
        int krow = second ? (((k & 7) << 4) | (k >> 3)) : k;
        v[j] = (_Float16)W[krow * 128 + col];
    }
    F[t] = __builtin_bit_cast(uint4, v);
}

// ---------------- MFMA GEMM: T8[r, p] = fp8( dinv[r] * (A[r,:] @ W) ), permuted p ----
template <bool HALF_IN>
__global__ __launch_bounds__(256) void gemm_mfma(const void* __restrict__ Ap,
                                                 const uint4* __restrict__ F,
                                                 const float* __restrict__ dinv,
                                                 unsigned char* __restrict__ T8, int n) {
    int w = threadIdx.x >> 6, lane = threadIdx.x & 63;
    int r0 = blockIdx.x * 128 + w * 32;
    int rA0 = r0 + (lane & 15);
    int rA1 = rA0 + 16;
    int kc = lane >> 4;
    floatx4 acc[2][8] = {};

#pragma unroll
    for (int ks = 0; ks < 4; ks++) {
        half8 a0 = {}, a1 = {};
        if constexpr (HALF_IN) {
            const uint4* A4 = (const uint4*)Ap;
            if (rA0 < n) a0 = __builtin_bit_cast(half8, A4[(size_t)rA0 * 16 + ks * 4 + kc]);
            if (rA1 < n) a1 = __builtin_bit_cast(half8, A4[(size_t)rA1 * 16 + ks * 4 + kc]);
        } else {
            const float* Af = (const float*)Ap;
            if (rA0 < n) {
                const float4* p = (const float4*)&Af[(size_t)rA0 * 128 + ks * 32 + kc * 8];
                float4 u = p[0], v = p[1];
                a0[0] = (_Float16)u.x; a0[1] = (_Float16)u.y; a0[2] = (_Float16)u.z; a0[3] = (_Float16)u.w;
                a0[4] = (_Float16)v.x; a0[5] = (_Float16)v.y; a0[6] = (_Float16)v.z; a0[7] = (_Float16)v.w;
            }
            if (rA1 < n) {
                const float4* p = (const float4*)&Af[(size_t)rA1 * 128 + ks * 32 + kc * 8];
                float4 u = p[0], v = p[1];
                a1[0] = (_Float16)u.x; a1[1] = (_Float16)u.y; a1[2] = (_Float16)u.z; a1[3] = (_Float16)u.w;
                a1[4] = (_Float16)v.x; a1[5] = (_Float16)v.y; a1[6] = (_Float16)v.z; a1[7] = (_Float16)v.w;
            }
        }
        half8 b[8];
#pragma unroll
        for (int ct = 0; ct < 8; ct++)
            b[ct] = __builtin_bit_cast(half8, F[ks * 512 + ct * 64 + lane]);
#pragma unroll
        for (int ct = 0; ct < 8; ct++) {
            acc[0][ct] = __builtin_amdgcn_mfma_f32_16x16x32_f16(a0, b[ct], acc[0][ct], 0, 0, 0);
            acc[1][ct] = __builtin_amdgcn_mfma_f32_16x16x32_f16(a1, b[ct], acc[1][ct], 0, 0, 0);
        }
    }

    int c = lane & 15;
#pragma unroll
    for (int rt = 0; rt < 2; rt++) {
        int rbase = r0 + rt * 16 + (lane >> 4) * 4;
#pragma unroll
        for (int reg = 0; reg < 4; reg++) {
            int r = rbase + reg;
            if (r < n) {
                float di = dinv[r];
                float vv[8];
#pragma unroll
                for (int ct = 0; ct < 8; ct++) vv[ct] = acc[rt][ct][reg] * di;
                int d0 = __builtin_amdgcn_cvt_pk_fp8_f32(vv[0], vv[1], 0, false);
                d0 = __builtin_amdgcn_cvt_pk_fp8_f32(vv[2], vv[3], d0, true);
                int d1 = __builtin_amdgcn_cvt_pk_fp8_f32(vv[4], vv[5], 0, false);
                d1 = __builtin_amdgcn_cvt_pk_fp8_f32(vv[6], vv[7], d1, true);
                *(uint2*)(T8 + (size_t)r * 128 + c * 8) = make_uint2((unsigned)d0, (unsigned)d1);
            }
        }
    }
}

// ---------------- aggregation: wave/node over padded fp8 CSR ----------------
// 16 lanes/edge, 8 edges/step; group g loads its OWN index (csrP[e+j+g] — 8
// consecutive dwords/wave, L1 broadcast within group; no shuffles). Dual chains.
__global__ __launch_bounds__(256) void aggregate(const unsigned char* __restrict__ T8,
                                                 const int* __restrict__ csrP,
                                                 const int* __restrict__ rowptrP,
                                                 const int* __restrict__ rowEndP,
                                                 const float* __restrict__ dinv,
                                                 const float* __restrict__ bias,
                                                 unsigned int* __restrict__ Out, int n) {
    int node = (int)((blockIdx.x * 256 + threadIdx.x) >> 6);
    int lane = threadIdx.x & 63;
    if (node >= n) return;
    int grp = lane >> 4, m = lane & 15;
    unsigned mo = (unsigned)m << 3;

    floatx2 acc[4] = {}, acc2[4] = {};
    int e = rowptrP[node], end = rowEndP[node];   // end-e multiple of 8
    while (e < end) {
        int take = min(end - e, 64);     // multiple of 8, wave-uniform
#pragma unroll 2
        for (int j = 0; j < take; j += 8) {
            int sA = csrP[e + j + grp];
            int sB = csrP[e + j + 4 + grp];
            uint2 vA = *(const uint2*)(T8 + (((unsigned)sA << 7) | mo));
            uint2 vB = *(const uint2*)(T8 + (((unsigned)sB << 7) | mo));
            fp8_acc8(acc, vA);
            fp8_acc8(acc2, vB);
        }
        e += take;
    }
#pragma unroll
    for (int q = 0; q < 4; q++) acc[q] += acc2[q];
    float* af = (float*)acc;
#pragma unroll
    for (int q = 0; q < 8; q++) {
        af[q] += __shfl_xor(af[q], 16);
        af[q] += __shfl_xor(af[q], 32);
    }

    // epilogue: byte pair q = m*8 + 2*grp -> acc slot grp; dim = grp*32 + m (+16)
    floatx2 a = acc[grp];
    int dim = (grp << 5) | m;
    float di = dinv[node];
    float o0 = tanh_fast(a.x * di + bias[dim]);
    float o1 = tanh_fast(a.y * di + bias[dim + 16]);
    Out[(size_t)node * 64 + m * 4 + grp] =
        __builtin_bit_cast(unsigned int, __floats2half2_rn(o0, o1));
}

// same, fused with classifier head: logits[node] = tanh(h)·Wc + bc
__global__ __launch_bounds__(256) void aggregate_logits(const unsigned char* __restrict__ T8,
                                                        const int* __restrict__ csrP,
                                                        const int* __restrict__ rowptrP,
                                                        const int* __restrict__ rowEndP,
                                                        const float* __restrict__ dinv,
                                                        const float* __restrict__ bias,
                                                        const float* __restrict__ Wc,
                                                        const float* __restrict__ bc,
                                                        float* __restrict__ logits, int n) {
    int node = (int)((blockIdx.x * 256 + threadIdx.x) >> 6);
    int lane = threadIdx.x & 63;
    if (node >= n) return;
    int grp = lane >> 4, m = lane & 15;
    unsigned mo = (unsigned)m << 3;

    floatx2 acc[4] = {}, acc2[4] = {};
    int e = rowptrP[node], end = rowEndP[node];
    while (e < end) {
        int take = min(end - e, 64);
#pragma unroll 2
        for (int j = 0; j < take; j += 8) {
            int sA = csrP[e + j + grp];
            int sB = csrP[e + j + 4 + grp];
            uint2 vA = *(const uint2*)(T8 + (((unsigned)sA << 7) | mo));
            uint2 vB = *(const uint2*)(T8 + (((unsigned)sB << 7) | mo));
            fp8_acc8(acc, vA);
            fp8_acc8(acc2, vB);
        }
        e += take;
    }
#pragma unroll
    for (int q = 0; q < 4; q++) acc[q] += acc2[q];
    float* af = (float*)acc;
#pragma unroll
    for (int q = 0; q < 8; q++) {
        af[q] += __shfl_xor(af[q], 16);
        af[q] += __shfl_xor(af[q], 32);
    }

    floatx2 a = acc[grp];
    int dim = (grp << 5) | m;
    float di = dinv[node];
    float d = tanh_fast(a.x * di + bias[dim]) * Wc[dim]
            + tanh_fast(a.y * di + bias[dim + 16]) * Wc[dim + 16];
#pragma unroll
    for (int off = 1; off < 64; off <<= 1) d += __shfl_xor(d, off);
    if (lane == 0) logits[node] = d + bc[0];
}

// ---------------- softmax over N ----------------
__global__ __launch_bounds__(256) void maxpart(const float* __restrict__ logits, int n,
                                               float* __restrict__ partialMax,
                                               float* __restrict__ denom) {
    if (blockIdx.x == 0 && threadIdx.x == 0) *denom = 0.0f;
    __shared__ float s[256];
    float m = -3.4e38f;
    for (int i = blockIdx.x * 256 + threadIdx.x; i < n; i += 256 * 256)
        m = fmaxf(m, logits[i]);
    s[threadIdx.x] = m;
    __syncthreads();
    for (int d = 128; d; d >>= 1) {
        if (threadIdx.x < d) s[threadIdx.x] = fmaxf(s[threadIdx.x], s[threadIdx.x + d]);
        __syncthreads();
    }
    if (threadIdx.x == 0) partialMax[blockIdx.x] = s[0];
}

__global__ __launch_bounds__(256) void exp_kernel(const float* __restrict__ logits,
                                                  const float* __restrict__ partialMax,
                                                  float* __restrict__ outv,
                                                  float* __restrict__ denom, int n) {
    __shared__ float s[256];
    s[threadIdx.x] = partialMax[threadIdx.x];
    __syncthreads();
    for (int d = 128; d; d >>= 1) {
        if (threadIdx.x < d) s[threadIdx.x] = fmaxf(s[threadIdx.x], s[threadIdx.x + d]);
        __syncthreads();
    }
    float maxv = s[0];
    __syncthreads();
    int i = blockIdx.x * 256 + threadIdx.x;
    float e = 0.0f;
    if (i < n) {
        e = expf(logits[i] - maxv);
        outv[i] = e;
    }
    s[threadIdx.x] = e;
    __syncthreads();
    for (int d = 128; d; d >>= 1) {
        if (threadIdx.x < d) s[threadIdx.x] += s[threadIdx.x + d];
        __syncthreads();
    }
    if (threadIdx.x == 0) atomicAdd(denom, s[0]);
}

__global__ __launch_bounds__(256) void norm_kernel(float* __restrict__ out,
                                                   const float* __restrict__ denom, int n) {
    int i = blockIdx.x * 256 + threadIdx.x;
    if (i < n) out[i] = out[i] / (*denom);
}

extern "C" void kernel_launch(void* const* d_in, const int* in_sizes, int n_in,
                              void* d_out, int out_size, void* d_ws, size_t ws_size,
                              hipStream_t stream) {
    const float* x  = (const float*)d_in[0];
    const int*   ei = (const int*)d_in[1];   // [2,E] int32 (JAX x64 disabled)
    const float* W1 = (const float*)d_in[2];
    const float* b1 = (const float*)d_in[3];
    const float* W2 = (const float*)d_in[4];
    const float* b2 = (const float*)d_in[5];
    const float* Wc = (const float*)d_in[6];
    const float* bc = (const float*)d_in[7];

    int n = in_sizes[0] / 128;
    int E = in_sizes[1] / 2;
    const int* row = ei;
    const int* col = ei + E;
    int NB = (n + BSPAN - 1) >> BSHIFT;

    char* ws = (char*)d_ws;
    size_t off = 0;
    auto alloc = [&](size_t bytes) -> void* {
        void* p = ws + off;
        off += (bytes + 255) & ~(size_t)255;
        return p;
    };
    unsigned char* T1 = (unsigned char*)alloc((size_t)(n + 1) * 128);  // fp8 (+zero row)
    unsigned char* T2 = (unsigned char*)alloc((size_t)(n + 1) * 128);
    unsigned int*  H1 = (unsigned int*)alloc((size_t)n * 128 * 2);     // fp16 h1 (permuted)
    int*    csrP     = (int*)alloc(((size_t)E + (size_t)NB * BPAD + 64) * 4);
    unsigned int* pairs = (unsigned int*)alloc((size_t)E * 4);
    float*  dinv     = (float*)alloc((size_t)n * 4);
    int*    rowptrP  = (int*)alloc((size_t)(n + 1) * 4);
    int*    rowEndP  = (int*)alloc((size_t)n * 4);
    int*    bucketCnt= (int*)alloc(256 * 4);
    int*    bucketPtr= (int*)alloc(257 * 4);
    int*    cursor   = (int*)alloc(256 * 4);
    uint4*  F1       = (uint4*)alloc(2048 * 16);
    uint4*  F2       = (uint4*)alloc(2048 * 16);
    float*  logits   = (float*)alloc((size_t)n * 4);
    float*  pmax     = (float*)alloc(256 * 4);
    float*  denom    = (float*)alloc(4);

    int nbN = (n + 255) / 256;
    int nbW = (n + 3) / 4;
    int nbG = (n + 127) / 128;

    hipMemsetAsync(bucketCnt, 0, 256 * 4, stream);

    hist_buckets<<<512, 256, 0, stream>>>(col, E, bucketCnt);
    scan_buckets<<<1, 256, 0, stream>>>(bucketCnt, bucketPtr, cursor, NB, E);
    partition_edges<<<(E + PCHUNK - 1) / PCHUNK, 256, 0, stream>>>(row, col, E, cursor, pairs);
    prep_wfrags<<<17, 256, 0, stream>>>(W1, W2, F1, F2, T1, T2, n);
    build_bucket_csr<<<NB, 256, 0, stream>>>(pairs, bucketPtr, rowptrP, rowEndP, dinv,
                                             csrP, n, NB, E);

    gemm_mfma<false><<<nbG, 256, 0, stream>>>(x, F1, dinv, T1, n);
    aggregate<<<nbW, 256, 0, stream>>>(T1, csrP, rowptrP, rowEndP, dinv, b1, H1, n);
    gemm_mfma<true><<<nbG, 256, 0, stream>>>(H1, F2, dinv, T2, n);
    aggregate_logits<<<nbW, 256, 0, stream>>>(T2, csrP, rowptrP, rowEndP, dinv, b2, Wc, bc,
                                              logits, n);

    maxpart<<<256, 256, 0, stream>>>(logits, n, pmax, denom);
    exp_kernel<<<nbN, 256, 0, stream>>>(logits, pmax, (float*)d_out, denom, n);
    norm_kernel<<<nbN, 256, 0, stream>>>((float*)d_out, denom, n);
}